// Round 5
// baseline (4311.266 us; speedup 1.0000x reference)
//
#include <hip/hip_runtime.h>
#include <hip/hip_bf16.h>
#include <math.h>

#define NB 16
#define CIN1 512
#define COUT 256
#define GD 256
#define TD 256
#define LL 32
#define P1 1024
#define P2 4096
#define CONDC 512

// ---------------- BN stats: mean + rsqrt(var+eps) per channel ----------------
__global__ void bn_stats_kernel(const float* __restrict__ x, float* __restrict__ mean,
                                float* __restrict__ rstd, int C, int HW) {
  int c = blockIdx.x, t = threadIdx.x;
  float s = 0.f, sq = 0.f;
  for (int b = 0; b < NB; ++b) {
    const float* p = x + ((size_t)b * C + c) * HW;
    for (int i = t; i < HW; i += 256) { float v = p[i]; s += v; sq += v * v; }
  }
  __shared__ float ss[256], sq2[256];
  ss[t] = s; sq2[t] = sq; __syncthreads();
  for (int o = 128; o > 0; o >>= 1) {
    if (t < o) { ss[t] += ss[t + o]; sq2[t] += sq2[t + o]; }
    __syncthreads();
  }
  if (t == 0) {
    float n = (float)NB * (float)HW;
    float m = ss[0] / n;
    float v = sq2[0] / n - m * m;
    mean[c] = m;
    rstd[c] = rsqrtf(v + 1e-5f);
  }
}

// ---------------- normalize words_embs over channel dim per (b,l) ----------------
__global__ void wdn_kernel(const float* __restrict__ we, float* __restrict__ wdn) {
  int b = blockIdx.x >> 5, l = blockIdx.x & 31;
  int t = threadIdx.x; // 64
  const float* base = we + (size_t)b * TD * LL + l;
  float v[4]; float sq = 0.f;
#pragma unroll
  for (int k = 0; k < 4; ++k) { v[k] = base[(size_t)(t * 4 + k) * LL]; sq += v[k] * v[k]; }
#pragma unroll
  for (int o = 32; o > 0; o >>= 1) sq += __shfl_xor(sq, o);
  float r = 1.f / fmaxf(sqrtf(sq), 1e-12f);
  float* ob = wdn + (size_t)b * TD * LL + l;
#pragma unroll
  for (int k = 0; k < 4; ++k) ob[(size_t)(t * 4 + k) * LL] = v[k] * r;
}

// ---------------- per-pixel: l2norm(img col) -> sim vs wdn -> mask -> softmax ----------------
__global__ __launch_bounds__(256) void attn_kernel(const float* __restrict__ img,
                                                   const float* __restrict__ wdn,
                                                   const int* __restrict__ mask,
                                                   float* __restrict__ attn, int P) {
  __shared__ float imgs[4][TD];
  int wv = threadIdx.x >> 6, lane = threadIdx.x & 63;
  int p = blockIdx.x * 4 + wv, b = blockIdx.y;
  const float* ib = img + (size_t)b * TD * P + p;
  float v[4]; float sq = 0.f;
#pragma unroll
  for (int k = 0; k < 4; ++k) { v[k] = ib[(size_t)(lane * 4 + k) * P]; sq += v[k] * v[k]; }
#pragma unroll
  for (int o = 32; o > 0; o >>= 1) sq += __shfl_xor(sq, o);
  float rn = 1.f / fmaxf(sqrtf(sq), 1e-12f);
  *(float4*)&imgs[wv][lane * 4] = make_float4(v[0], v[1], v[2], v[3]);
  __syncthreads();
  int l = lane & 31, half = lane >> 5;
  const float* wb = wdn + (size_t)b * TD * LL + l;
  float sim = 0.f;
  int c0 = half * 128;
#pragma unroll 8
  for (int c = 0; c < 128; ++c) sim += imgs[wv][c0 + c] * wb[(size_t)(c0 + c) * LL];
  sim += __shfl_xor(sim, 32);
  sim *= rn;
  if (mask[b * LL + l] != 0) sim = -INFINITY;
  float m = sim;
#pragma unroll
  for (int o = 16; o > 0; o >>= 1) m = fmaxf(m, __shfl_xor(m, o));
  float e = expf(sim - m);
  float s = e;
#pragma unroll
  for (int o = 16; o > 0; o >>= 1) s += __shfl_xor(s, o);
  float a = e / s;
  if (half == 0) attn[((size_t)b * P + p) * LL + l] = a;
}

// ---------------- ctx[b,c,p] = sum_l attn[b,p,l]*wdn[b,c,l] ----------------
__global__ __launch_bounds__(256) void ctx_kernel(const float* __restrict__ attn,
                                                  const float* __restrict__ wdn,
                                                  float* __restrict__ ctx, int P) {
  __shared__ float wdns[TD * LL];   // 32 KB
  __shared__ float attns[64 * LL];  // 8 KB
  int b = blockIdx.y, p0 = blockIdx.x * 64, t = threadIdx.x;
  const float4* wsrc = (const float4*)(wdn + (size_t)b * TD * LL);
  for (int i = t; i < TD * LL / 4; i += 256) ((float4*)wdns)[i] = wsrc[i];
  const float4* asrc = (const float4*)(attn + ((size_t)b * P + p0) * LL);
  for (int i = t; i < 64 * LL / 4; i += 256) ((float4*)attns)[i] = asrc[i];
  __syncthreads();
  int pi = t & 63, cg = t >> 6;
  float a[LL];
#pragma unroll
  for (int l = 0; l < LL; l += 4) {
    float4 q = *(float4*)&attns[pi * LL + l];
    a[l] = q.x; a[l + 1] = q.y; a[l + 2] = q.z; a[l + 3] = q.w;
  }
  for (int k = 0; k < 64; ++k) {
    int c = cg * 64 + k;
    float acc = 0.f;
#pragma unroll
    for (int l = 0; l < LL; l += 4) {
      float4 w4 = *(float4*)&wdns[c * LL + l];
      acc += a[l] * w4.x + a[l + 1] * w4.y + a[l + 2] * w4.z + a[l + 3] * w4.w;
    }
    ctx[((size_t)b * TD + c) * P + p0 + pi] = acc;
  }
}

// ---------------- gvec[b,o] = bias[o] + sum_{c<GD} W[o,c]*gc[b,c] ----------------
__global__ void gvec_kernel(const float* __restrict__ Wg, const float* __restrict__ bias,
                            const float* __restrict__ gc, float* __restrict__ outv, int O) {
  int o = blockIdx.x * 64 + threadIdx.x;
  int b = blockIdx.y;
  if (o >= O) return;
  const float* wr = Wg + (size_t)o * CONDC;
  const float* g = gc + (size_t)b * GD;
  float s = 0.f;
  for (int c = 0; c < GD; ++c) s += wr[c] * g[c];
  outv[(size_t)b * O + o] = s + bias[o];
}

// ---------------- Y[b,t,p] = vec[b,t] + sum_c W[t, c_off+c] * X[b,c,p] ----------------
__global__ __launch_bounds__(256) void gemm_wx_kernel(
    const float* __restrict__ W, int ldw, int c_off,
    const float* __restrict__ X, const float* __restrict__ vec,
    float* __restrict__ Y, int T, int C, int P) {
  __shared__ float Ws[16][68];
  __shared__ float Xs[16][64];
  int b = blockIdx.z;
  int t0 = blockIdx.y * 64, p0 = blockIdx.x * 64;
  int tid = threadIdx.x;
  const float* Xb = X + (size_t)b * C * P;
  int wrow = tid >> 2, wcg = tid & 3;
  int xrow = tid >> 4, xcol = (tid & 15) << 2;
  int ty = tid >> 4, tx = tid & 15;
  float acc[4][4] = {};
  for (int k0 = 0; k0 < C; k0 += 16) {
    float4 wv = *(const float4*)(W + (size_t)(t0 + wrow) * ldw + c_off + k0 + (wcg << 2));
    Ws[wcg * 4 + 0][wrow] = wv.x; Ws[wcg * 4 + 1][wrow] = wv.y;
    Ws[wcg * 4 + 2][wrow] = wv.z; Ws[wcg * 4 + 3][wrow] = wv.w;
    *(float4*)&Xs[xrow][xcol] = *(const float4*)(Xb + (size_t)(k0 + xrow) * P + p0 + xcol);
    __syncthreads();
#pragma unroll
    for (int j = 0; j < 16; ++j) {
      float4 wr = *(const float4*)&Ws[j][ty << 2];
      float4 xr = *(const float4*)&Xs[j][tx << 2];
      acc[0][0] += wr.x * xr.x; acc[0][1] += wr.x * xr.y; acc[0][2] += wr.x * xr.z; acc[0][3] += wr.x * xr.w;
      acc[1][0] += wr.y * xr.x; acc[1][1] += wr.y * xr.y; acc[1][2] += wr.y * xr.z; acc[1][3] += wr.y * xr.w;
      acc[2][0] += wr.z * xr.x; acc[2][1] += wr.z * xr.y; acc[2][2] += wr.z * xr.z; acc[2][3] += wr.z * xr.w;
      acc[3][0] += wr.w * xr.x; acc[3][1] += wr.w * xr.y; acc[3][2] += wr.w * xr.z; acc[3][3] += wr.w * xr.w;
    }
    __syncthreads();
  }
  float bias[4] = {0.f, 0.f, 0.f, 0.f};
  if (vec) {
#pragma unroll
    for (int i = 0; i < 4; ++i) bias[i] = vec[(size_t)b * T + t0 + ty * 4 + i];
  }
#pragma unroll
  for (int i = 0; i < 4; ++i) {
    float4 o4 = make_float4(acc[i][0] + bias[i], acc[i][1] + bias[i],
                            acc[i][2] + bias[i], acc[i][3] + bias[i]);
    *(float4*)(Y + ((size_t)b * T + t0 + ty * 4 + i) * P + p0 + (tx << 2)) = o4;
  }
}

// ---------------- fused: relu(gamma * BN(x) + beta) ----------------
__global__ void act_kernel(const float* __restrict__ xin, const float* __restrict__ gamma,
                           const float* __restrict__ beta, const float* __restrict__ mean,
                           const float* __restrict__ rstd, const float* __restrict__ bnw,
                           const float* __restrict__ bnb, float* __restrict__ out,
                           int C, int P, int n4) {
  int i = blockIdx.x * 256 + threadIdx.x;
  if (i >= n4) return;
  int c = ((i << 2) / P) % C;
  float4 xv = ((const float4*)xin)[i];
  float4 g = ((const float4*)gamma)[i];
  float4 bt = ((const float4*)beta)[i];
  float m = mean[c], r = rstd[c] * bnw[c], bb = bnb[c];
  float4 o;
  o.x = fmaxf(g.x * ((xv.x - m) * r + bb) + bt.x, 0.f);
  o.y = fmaxf(g.y * ((xv.y - m) * r + bb) + bt.y, 0.f);
  o.z = fmaxf(g.z * ((xv.z - m) * r + bb) + bt.z, 0.f);
  o.w = fmaxf(g.w * ((xv.w - m) * r + bb) + bt.w, 0.f);
  ((float4*)out)[i] = o;
}

// ---------------- implicit-GEMM 3x3 conv, optional nearest-up2 input, optional shortcut epilogue ----------------
template <int CIN, bool UP>
__global__ __launch_bounds__(256) void conv3_kernel(
    const float* __restrict__ Wc, const float* __restrict__ Xin,
    const float* __restrict__ scs, const float* __restrict__ scb,
    float* __restrict__ Y) {
  const int K = CIN * 9;
  const int S = UP ? 32 : 64;
  __shared__ float Ws[16][68];
  __shared__ float Xs[16][64];
  int b = blockIdx.z;
  int o0 = blockIdx.y * 64;
  int y = blockIdx.x;  // output row 0..63
  int tid = threadIdx.x;
  int wrow = tid >> 2, wcg = tid & 3;
  int jrow = tid >> 4, xi0 = (tid & 15) << 2;
  int ty = tid >> 4, tx = tid & 15;
  float acc[4][4] = {};
  const float* Xb = Xin + (size_t)b * CIN * S * S;
  for (int k0 = 0; k0 < K; k0 += 16) {
    float4 wv = *(const float4*)(Wc + (size_t)(o0 + wrow) * K + k0 + (wcg << 2));
    Ws[wcg * 4 + 0][wrow] = wv.x; Ws[wcg * 4 + 1][wrow] = wv.y;
    Ws[wcg * 4 + 2][wrow] = wv.z; Ws[wcg * 4 + 3][wrow] = wv.w;
    {
      int kk = k0 + jrow;
      int c = kk / 9, r = kk - c * 9;
      int ky = r / 3, kx = r - ky * 3;
      int uy = y + ky - 1;
      bool yok = (uy >= 0 && uy < 64);
      int sy = UP ? (uy >> 1) : uy;
      float4 xv;
      float* xd = (float*)&xv;
#pragma unroll
      for (int u = 0; u < 4; ++u) {
        int ux = xi0 + u + kx - 1;
        bool ok = yok && (ux >= 0) && (ux < 64);
        int sx = UP ? (ux >> 1) : ux;
        xd[u] = ok ? Xb[((size_t)c * S + sy) * S + sx] : 0.f;
      }
      *(float4*)&Xs[jrow][xi0] = xv;
    }
    __syncthreads();
#pragma unroll
    for (int j = 0; j < 16; ++j) {
      float4 wr = *(const float4*)&Ws[j][ty << 2];
      float4 xr = *(const float4*)&Xs[j][tx << 2];
      acc[0][0] += wr.x * xr.x; acc[0][1] += wr.x * xr.y; acc[0][2] += wr.x * xr.z; acc[0][3] += wr.x * xr.w;
      acc[1][0] += wr.y * xr.x; acc[1][1] += wr.y * xr.y; acc[1][2] += wr.y * xr.z; acc[1][3] += wr.y * xr.w;
      acc[2][0] += wr.z * xr.x; acc[2][1] += wr.z * xr.y; acc[2][2] += wr.z * xr.z; acc[2][3] += wr.z * xr.w;
      acc[3][0] += wr.w * xr.x; acc[3][1] += wr.w * xr.y; acc[3][2] += wr.w * xr.z; acc[3][3] += wr.w * xr.w;
    }
    __syncthreads();
  }
#pragma unroll
  for (int i = 0; i < 4; ++i) {
    int o = o0 + ty * 4 + i;
    float4 o4 = make_float4(acc[i][0], acc[i][1], acc[i][2], acc[i][3]);
    if (scs) {
      float bias = scb[o];
      const float* sb = scs + ((size_t)b * COUT + o) * P1 + (size_t)(y >> 1) * 32;
      int x0 = tx << 2;
      o4.x += sb[(x0 + 0) >> 1] + bias;
      o4.y += sb[(x0 + 1) >> 1] + bias;
      o4.z += sb[(x0 + 2) >> 1] + bias;
      o4.w += sb[(x0 + 3) >> 1] + bias;
    }
    *(float4*)(Y + ((size_t)b * COUT + o) * 4096 + y * 64 + (tx << 2)) = o4;
  }
}

extern "C" void kernel_launch(void* const* d_in, const int* in_sizes, int n_in,
                              void* d_out, int out_size, void* d_ws, size_t ws_size,
                              hipStream_t stream) {
  const float* x      = (const float*)d_in[0];
  const float* gcond  = (const float*)d_in[1];
  const float* wemb   = (const float*)d_in[2];
  const int*   mask   = (const int*)d_in[3];
  const float* w_img1 = (const float*)d_in[4];
  const float* w_img2 = (const float*)d_in[5];
  const float* w_c1   = (const float*)d_in[6];
  const float* w_c2   = (const float*)d_in[7];
  const float* bn1_w  = (const float*)d_in[8];
  const float* bn1_b  = (const float*)d_in[9];
  const float* bn2_w  = (const float*)d_in[10];
  const float* bn2_b  = (const float*)d_in[11];
  const float* w_g1   = (const float*)d_in[12];
  const float* b_g1   = (const float*)d_in[13];
  const float* w_b1   = (const float*)d_in[14];
  const float* b_b1   = (const float*)d_in[15];
  const float* w_g2   = (const float*)d_in[16];
  const float* b_g2   = (const float*)d_in[17];
  const float* w_b2   = (const float*)d_in[18];
  const float* b_b2   = (const float*)d_in[19];
  const float* w_sc   = (const float*)d_in[20];
  const float* b_sc   = (const float*)d_in[21];
  float* out = (float*)d_out;
  float* ws = (float*)d_ws;

  const size_t MF = 16777216;  // floats per 64MB region
  float* A  = ws;
  float* Br = ws + MF;
  float* Cr = ws + 2 * MF;
  float* SM = ws + 3 * MF;
  float* wdn   = SM;                     // 131072
  float* attnb = SM + 131072;            // up to 2097152
  float* mean1 = attnb + 2097152;
  float* rstd1 = mean1 + 512;
  float* mean2 = rstd1 + 512;
  float* rstd2 = mean2 + 256;
  float* gvec1 = rstd2 + 256;            // 8192
  float* bvec1 = gvec1 + 8192;
  float* gvec2 = bvec1 + 8192;           // 4096
  float* bvec2 = gvec2 + 4096;

  float* img1   = A;                // 4M floats
  float* ctx1   = A + 4194304;      // 4M
  float* act1   = A + 8388608;      // 8M
  float* gamma1 = Br;               // 8M
  float* beta1  = Br + 8388608;     // 8M
  float* conv1o = Cr;               // 16M
  float* img2   = A;                // reuse (stage-1 A dead)
  float* ctx2   = Br;               // reuse
  float* gamma2 = A;                // reuse (img2 dead after attn2)
  float* beta2  = out;              // d_out as scratch until final conv
  float* act2   = Br;               // reuse (ctx2 dead)
  float* scs    = Cr;               // reuse (conv1o dead after act2)

  // ---- stage 1 ----
  bn_stats_kernel<<<dim3(CIN1), dim3(256), 0, stream>>>(x, mean1, rstd1, CIN1, P1);
  wdn_kernel<<<dim3(NB * LL), dim3(64), 0, stream>>>(wemb, wdn);
  gemm_wx_kernel<<<dim3(P1 / 64, TD / 64, NB), dim3(256), 0, stream>>>(
      w_img1, CIN1, 0, x, nullptr, img1, TD, CIN1, P1);
  attn_kernel<<<dim3(P1 / 4, NB), dim3(256), 0, stream>>>(img1, wdn, mask, attnb, P1);
  ctx_kernel<<<dim3(P1 / 64, NB), dim3(256), 0, stream>>>(attnb, wdn, ctx1, P1);
  gvec_kernel<<<dim3(CIN1 / 64, NB), dim3(64), 0, stream>>>(w_g1, b_g1, gcond, gvec1, CIN1);
  gvec_kernel<<<dim3(CIN1 / 64, NB), dim3(64), 0, stream>>>(w_b1, b_b1, gcond, bvec1, CIN1);
  gemm_wx_kernel<<<dim3(P1 / 64, CIN1 / 64, NB), dim3(256), 0, stream>>>(
      w_g1, CONDC, GD, ctx1, gvec1, gamma1, CIN1, TD, P1);
  gemm_wx_kernel<<<dim3(P1 / 64, CIN1 / 64, NB), dim3(256), 0, stream>>>(
      w_b1, CONDC, GD, ctx1, bvec1, beta1, CIN1, TD, P1);
  act_kernel<<<dim3(NB * CIN1 * P1 / 4 / 256), dim3(256), 0, stream>>>(
      x, gamma1, beta1, mean1, rstd1, bn1_w, bn1_b, act1, CIN1, P1, NB * CIN1 * P1 / 4);
  conv3_kernel<CIN1, true><<<dim3(64, COUT / 64, NB), dim3(256), 0, stream>>>(
      w_c1, act1, nullptr, nullptr, conv1o);

  // ---- stage 2 ----
  bn_stats_kernel<<<dim3(COUT), dim3(256), 0, stream>>>(conv1o, mean2, rstd2, COUT, P2);
  gemm_wx_kernel<<<dim3(P2 / 64, TD / 64, NB), dim3(256), 0, stream>>>(
      w_img2, COUT, 0, conv1o, nullptr, img2, TD, COUT, P2);
  attn_kernel<<<dim3(P2 / 4, NB), dim3(256), 0, stream>>>(img2, wdn, mask, attnb, P2);
  ctx_kernel<<<dim3(P2 / 64, NB), dim3(256), 0, stream>>>(attnb, wdn, ctx2, P2);
  gvec_kernel<<<dim3(COUT / 64, NB), dim3(64), 0, stream>>>(w_g2, b_g2, gcond, gvec2, COUT);
  gvec_kernel<<<dim3(COUT / 64, NB), dim3(64), 0, stream>>>(w_b2, b_b2, gcond, bvec2, COUT);
  gemm_wx_kernel<<<dim3(P2 / 64, COUT / 64, NB), dim3(256), 0, stream>>>(
      w_g2, CONDC, GD, ctx2, gvec2, gamma2, COUT, TD, P2);
  gemm_wx_kernel<<<dim3(P2 / 64, COUT / 64, NB), dim3(256), 0, stream>>>(
      w_b2, CONDC, GD, ctx2, bvec2, beta2, COUT, TD, P2);
  act_kernel<<<dim3(NB * COUT * P2 / 4 / 256), dim3(256), 0, stream>>>(
      conv1o, gamma2, beta2, mean2, rstd2, bn2_w, bn2_b, act2, COUT, P2, NB * COUT * P2 / 4);
  gemm_wx_kernel<<<dim3(P1 / 64, COUT / 64, NB), dim3(256), 0, stream>>>(
      w_sc, CIN1, 0, x, nullptr, scs, COUT, CIN1, P1);
  conv3_kernel<COUT, false><<<dim3(64, COUT / 64, NB), dim3(256), 0, stream>>>(
      w_c2, act2, scs, b_sc, out);
}

// Round 6
// 1563.671 us; speedup vs baseline: 2.7571x; 2.7571x over previous
//
#include <hip/hip_runtime.h>
#include <hip/hip_bf16.h>
#include <math.h>

#define NB 16
#define CIN1 512
#define COUT 256
#define GD 256
#define TD 256
#define LL 32
#define P1 1024
#define P2 4096
#define CONDC 512

typedef __attribute__((ext_vector_type(8))) short bf16x8;
typedef __attribute__((ext_vector_type(4))) float f32x4;
typedef unsigned short u16;

// ---------------- BN stats: mean + rsqrt(var+eps) per channel ----------------
__global__ void bn_stats_kernel(const float* __restrict__ x, float* __restrict__ mean,
                                float* __restrict__ rstd, int C, int HW) {
  int c = blockIdx.x, t = threadIdx.x;
  float s = 0.f, sq = 0.f;
  for (int b = 0; b < NB; ++b) {
    const float* p = x + ((size_t)b * C + c) * HW;
    for (int i = t; i < HW; i += 256) { float v = p[i]; s += v; sq += v * v; }
  }
  __shared__ float ss[256], sq2[256];
  ss[t] = s; sq2[t] = sq; __syncthreads();
  for (int o = 128; o > 0; o >>= 1) {
    if (t < o) { ss[t] += ss[t + o]; sq2[t] += sq2[t + o]; }
    __syncthreads();
  }
  if (t == 0) {
    float n = (float)NB * (float)HW;
    float m = ss[0] / n;
    float v = sq2[0] / n - m * m;
    mean[c] = m;
    rstd[c] = rsqrtf(v + 1e-5f);
  }
}

// ---------------- normalize words_embs over channel dim per (b,l) ----------------
__global__ void wdn_kernel(const float* __restrict__ we, float* __restrict__ wdn) {
  int b = blockIdx.x >> 5, l = blockIdx.x & 31;
  int t = threadIdx.x; // 64
  const float* base = we + (size_t)b * TD * LL + l;
  float v[4]; float sq = 0.f;
#pragma unroll
  for (int k = 0; k < 4; ++k) { v[k] = base[(size_t)(t * 4 + k) * LL]; sq += v[k] * v[k]; }
#pragma unroll
  for (int o = 32; o > 0; o >>= 1) sq += __shfl_xor(sq, o);
  float r = 1.f / fmaxf(sqrtf(sq), 1e-12f);
  float* ob = wdn + (size_t)b * TD * LL + l;
#pragma unroll
  for (int k = 0; k < 4; ++k) ob[(size_t)(t * 4 + k) * LL] = v[k] * r;
}

// ---------------- per-pixel: l2norm(img col) -> sim vs wdn -> mask -> softmax ----------------
__global__ __launch_bounds__(256) void attn_kernel(const float* __restrict__ img,
                                                   const float* __restrict__ wdn,
                                                   const int* __restrict__ mask,
                                                   float* __restrict__ attn, int P) {
  __shared__ float imgs[4][TD];
  int wv = threadIdx.x >> 6, lane = threadIdx.x & 63;
  int p = blockIdx.x * 4 + wv, b = blockIdx.y;
  const float* ib = img + (size_t)b * TD * P + p;
  float v[4]; float sq = 0.f;
#pragma unroll
  for (int k = 0; k < 4; ++k) { v[k] = ib[(size_t)(lane * 4 + k) * P]; sq += v[k] * v[k]; }
#pragma unroll
  for (int o = 32; o > 0; o >>= 1) sq += __shfl_xor(sq, o);
  float rn = 1.f / fmaxf(sqrtf(sq), 1e-12f);
  *(float4*)&imgs[wv][lane * 4] = make_float4(v[0], v[1], v[2], v[3]);
  __syncthreads();
  int l = lane & 31, half = lane >> 5;
  const float* wb = wdn + (size_t)b * TD * LL + l;
  float sim = 0.f;
  int c0 = half * 128;
#pragma unroll 8
  for (int c = 0; c < 128; ++c) sim += imgs[wv][c0 + c] * wb[(size_t)(c0 + c) * LL];
  sim += __shfl_xor(sim, 32);
  sim *= rn;
  if (mask[b * LL + l] != 0) sim = -INFINITY;
  float m = sim;
#pragma unroll
  for (int o = 16; o > 0; o >>= 1) m = fmaxf(m, __shfl_xor(m, o));
  float e = expf(sim - m);
  float s = e;
#pragma unroll
  for (int o = 16; o > 0; o >>= 1) s += __shfl_xor(s, o);
  float a = e / s;
  if (half == 0) attn[((size_t)b * P + p) * LL + l] = a;
}

// ---------------- ctx[b,c,p] = sum_l attn[b,p,l]*wdn[b,c,l] ----------------
__global__ __launch_bounds__(256) void ctx_kernel(const float* __restrict__ attn,
                                                  const float* __restrict__ wdn,
                                                  float* __restrict__ ctx, int P) {
  __shared__ float wdns[TD * LL];   // 32 KB
  __shared__ float attns[64 * LL];  // 8 KB
  int b = blockIdx.y, p0 = blockIdx.x * 64, t = threadIdx.x;
  const float4* wsrc = (const float4*)(wdn + (size_t)b * TD * LL);
  for (int i = t; i < TD * LL / 4; i += 256) ((float4*)wdns)[i] = wsrc[i];
  const float4* asrc = (const float4*)(attn + ((size_t)b * P + p0) * LL);
  for (int i = t; i < 64 * LL / 4; i += 256) ((float4*)attns)[i] = asrc[i];
  __syncthreads();
  int pi = t & 63, cg = t >> 6;
  float a[LL];
#pragma unroll
  for (int l = 0; l < LL; l += 4) {
    float4 q = *(float4*)&attns[pi * LL + l];
    a[l] = q.x; a[l + 1] = q.y; a[l + 2] = q.z; a[l + 3] = q.w;
  }
  for (int k = 0; k < 64; ++k) {
    int c = cg * 64 + k;
    float acc = 0.f;
#pragma unroll
    for (int l = 0; l < LL; l += 4) {
      float4 w4 = *(float4*)&wdns[c * LL + l];
      acc += a[l] * w4.x + a[l + 1] * w4.y + a[l + 2] * w4.z + a[l + 3] * w4.w;
    }
    ctx[((size_t)b * TD + c) * P + p0 + pi] = acc;
  }
}

// ---------------- gvec[b,o] = bias[o] + sum_{c<GD} W[o,c]*gc[b,c] ----------------
__global__ void gvec_kernel(const float* __restrict__ Wg, const float* __restrict__ bias,
                            const float* __restrict__ gc, float* __restrict__ outv, int O) {
  int o = blockIdx.x * 64 + threadIdx.x;
  int b = blockIdx.y;
  if (o >= O) return;
  const float* wr = Wg + (size_t)o * CONDC;
  const float* g = gc + (size_t)b * GD;
  float s = 0.f;
  for (int c = 0; c < GD; ++c) s += wr[c] * g[c];
  outv[(size_t)b * O + o] = s + bias[o];
}

// ---------------- Y[b,t,p] = vec[b,t] + sum_c W[t, c_off+c] * X[b,c,p] ----------------
__global__ __launch_bounds__(256) void gemm_wx_kernel(
    const float* __restrict__ W, int ldw, int c_off,
    const float* __restrict__ X, const float* __restrict__ vec,
    float* __restrict__ Y, int T, int C, int P) {
  __shared__ float Ws[16][68];
  __shared__ float Xs[16][64];
  int b = blockIdx.z;
  int t0 = blockIdx.y * 64, p0 = blockIdx.x * 64;
  int tid = threadIdx.x;
  const float* Xb = X + (size_t)b * C * P;
  int wrow = tid >> 2, wcg = tid & 3;
  int xrow = tid >> 4, xcol = (tid & 15) << 2;
  int ty = tid >> 4, tx = tid & 15;
  float acc[4][4] = {};
  for (int k0 = 0; k0 < C; k0 += 16) {
    float4 wv = *(const float4*)(W + (size_t)(t0 + wrow) * ldw + c_off + k0 + (wcg << 2));
    Ws[wcg * 4 + 0][wrow] = wv.x; Ws[wcg * 4 + 1][wrow] = wv.y;
    Ws[wcg * 4 + 2][wrow] = wv.z; Ws[wcg * 4 + 3][wrow] = wv.w;
    *(float4*)&Xs[xrow][xcol] = *(const float4*)(Xb + (size_t)(k0 + xrow) * P + p0 + xcol);
    __syncthreads();
#pragma unroll
    for (int j = 0; j < 16; ++j) {
      float4 wr = *(const float4*)&Ws[j][ty << 2];
      float4 xr = *(const float4*)&Xs[j][tx << 2];
      acc[0][0] += wr.x * xr.x; acc[0][1] += wr.x * xr.y; acc[0][2] += wr.x * xr.z; acc[0][3] += wr.x * xr.w;
      acc[1][0] += wr.y * xr.x; acc[1][1] += wr.y * xr.y; acc[1][2] += wr.y * xr.z; acc[1][3] += wr.y * xr.w;
      acc[2][0] += wr.z * xr.x; acc[2][1] += wr.z * xr.y; acc[2][2] += wr.z * xr.z; acc[2][3] += wr.z * xr.w;
      acc[3][0] += wr.w * xr.x; acc[3][1] += wr.w * xr.y; acc[3][2] += wr.w * xr.z; acc[3][3] += wr.w * xr.w;
    }
    __syncthreads();
  }
  float bias[4] = {0.f, 0.f, 0.f, 0.f};
  if (vec) {
#pragma unroll
    for (int i = 0; i < 4; ++i) bias[i] = vec[(size_t)b * T + t0 + ty * 4 + i];
  }
#pragma unroll
  for (int i = 0; i < 4; ++i) {
    float4 o4 = make_float4(acc[i][0] + bias[i], acc[i][1] + bias[i],
                            acc[i][2] + bias[i], acc[i][3] + bias[i]);
    *(float4*)(Y + ((size_t)b * T + t0 + ty * 4 + i) * P + p0 + (tx << 2)) = o4;
  }
}

// ---------------- fused: relu(gamma*BN(x)+beta) -> NHWC bf16 (LDS transpose) ----------------
__global__ __launch_bounds__(256) void act_nhwc_kernel(
    const float* __restrict__ xin, const float* __restrict__ gamma,
    const float* __restrict__ beta, const float* __restrict__ mean,
    const float* __restrict__ rstd, const float* __restrict__ bnw,
    const float* __restrict__ bnb, u16* __restrict__ outb, int C, int P) {
  __shared__ u16 Ts[32][68];
  int b = blockIdx.z, c0 = blockIdx.y * 32, p0 = blockIdx.x * 64;
  int tid = threadIdx.x;
  { // phase 1: compute 32c x 64px tile, rows coalesced
    int cr = tid >> 3, pg = tid & 7;
    int c = c0 + cr;
    size_t base = ((size_t)b * C + c) * P + p0 + pg * 8;
    float m = mean[c], r = rstd[c] * bnw[c], bb = bnb[c];
    float4 x1 = *(const float4*)(xin + base), x2 = *(const float4*)(xin + base + 4);
    float4 g1 = *(const float4*)(gamma + base), g2 = *(const float4*)(gamma + base + 4);
    float4 t1 = *(const float4*)(beta + base), t2 = *(const float4*)(beta + base + 4);
    float xv[8] = {x1.x, x1.y, x1.z, x1.w, x2.x, x2.y, x2.z, x2.w};
    float gv[8] = {g1.x, g1.y, g1.z, g1.w, g2.x, g2.y, g2.z, g2.w};
    float bv[8] = {t1.x, t1.y, t1.z, t1.w, t2.x, t2.y, t2.z, t2.w};
#pragma unroll
    for (int j = 0; j < 8; ++j) {
      float o = fmaxf(gv[j] * ((xv[j] - m) * r + bb) + bv[j], 0.f);
      __hip_bfloat16 h = __float2bfloat16(o);
      Ts[cr][pg * 8 + j] = *(u16*)&h;
    }
  }
  __syncthreads();
  { // phase 2: write NHWC, c contiguous
    int pr = tid >> 2, cg = tid & 3;
    union { u16 u[8]; uint4 v; } pk;
#pragma unroll
    for (int j = 0; j < 8; ++j) pk.u[j] = Ts[cg * 8 + j][pr];
    *(uint4*)(outb + ((size_t)b * P + p0 + pr) * C + c0 + cg * 8) = pk.v;
  }
}

// ---------------- pack conv weights: w[o][c][ky][kx] fp32 -> Wp[pos][o][c] bf16 ----------------
__global__ void pack_w_kernel(const float* __restrict__ w, u16* __restrict__ wp, int O, int CIN) {
  int lin = blockIdx.x * 256 + threadIdx.x;
  if (lin >= O * CIN) return;
  int o = lin / CIN, c = lin - o * CIN;
  const float* src = w + (size_t)lin * 9;
#pragma unroll
  for (int pos = 0; pos < 9; ++pos) {
    __hip_bfloat16 h = __float2bfloat16(src[pos]);
    wp[((size_t)pos * O + o) * CIN + c] = *(u16*)&h;
  }
}

// ---------------- bf16 MFMA implicit-GEMM 3x3 conv ----------------
// Block: 4 waves = 128 o x 128 px (2 output rows). Wave: 4x4 frags of 16x16x32.
// A (weights) from global Wp[pos][o][c] bf16; B (input window) staged in LDS from NHWC bf16.
template <int CIN, bool UP>
__global__ __launch_bounds__(256) void conv_mfma_kernel(
    const u16* __restrict__ Wp, const u16* __restrict__ Xt,
    const float* __restrict__ scs, const float* __restrict__ scb,
    float* __restrict__ Y) {
  constexpr int S = UP ? 32 : 64;
  __shared__ u16 Xs[4 * 66 * 36];  // 4 rows x 66 cols x (32c + 4 pad) = 19008 B
  const int b = blockIdx.z, oT = blockIdx.y, pxT = blockIdx.x;
  const int tid = threadIdx.x;
  const int w = tid >> 6, lane = tid & 63;
  const int wo = w >> 1, wp = w & 1;
  const int l15 = lane & 15, lg = lane >> 4;
  const int Y0 = pxT * 2;
  const u16* Xb = Xt + (size_t)b * S * S * CIN;
  f32x4 acc[4][4] = {};

  for (int c0 = 0; c0 < CIN; c0 += 32) {
    // stage input window: rows Y0-1..Y0+2, cols -1..64, channels c0..c0+31
    for (int i = tid; i < 2112; i += 256) {  // 2112 = 4*66*8 chunks of 4 bf16
      int r = i / 528;                       // 528 = 66*8
      int rem = i - r * 528;
      int col = rem >> 3;
      int ch = rem & 7;
      int uy = Y0 - 1 + r, ux = col - 1;
      uint2 v = make_uint2(0u, 0u);
      if (uy >= 0 && uy < 64 && ux >= 0 && ux < 64) {
        int sy = UP ? (uy >> 1) : uy, sx = UP ? (ux >> 1) : ux;
        v = *(const uint2*)(Xb + ((size_t)sy * S + sx) * CIN + c0 + ch * 4);
      }
      *(uint2*)(Xs + (r * 66 + col) * 36 + ch * 4) = v;
    }
    __syncthreads();
#pragma unroll
    for (int ky = 0; ky < 3; ++ky) {
#pragma unroll
      for (int kx = 0; kx < 3; ++kx) {
        const int pos = ky * 3 + kx;
        const u16* wb = Wp + ((size_t)pos * COUT + oT * 128 + wo * 64) * CIN + c0 + lg * 8;
        bf16x8 a[4], bfr[4];
#pragma unroll
        for (int rr = 0; rr < 4; ++rr)
          a[rr] = *(const bf16x8*)(wb + (size_t)(rr * 16 + l15) * CIN);
        const int rowb = ((wp + ky) * 66 + kx) * 36 + lg * 8;
#pragma unroll
        for (int ss = 0; ss < 4; ++ss) {
          int idx = rowb + (ss * 16 + l15) * 36;
          union { uint2 q[2]; bf16x8 v; } u;
          u.q[0] = *(const uint2*)(Xs + idx);
          u.q[1] = *(const uint2*)(Xs + idx + 4);
          bfr[ss] = u.v;
        }
#pragma unroll
        for (int rr = 0; rr < 4; ++rr)
#pragma unroll
          for (int ss = 0; ss < 4; ++ss)
            acc[rr][ss] = __builtin_amdgcn_mfma_f32_16x16x32_bf16(a[rr], bfr[ss], acc[rr][ss], 0, 0, 0);
      }
    }
    __syncthreads();
  }
  // epilogue: C/D frag mapping col=lane&15 (px), row=(lane>>4)*4+reg (o)
  const int oBase = oT * 128 + wo * 64 + lg * 4;
  const int pxBase = pxT * 128 + wp * 64 + l15;
#pragma unroll
  for (int rr = 0; rr < 4; ++rr) {
#pragma unroll
    for (int ss = 0; ss < 4; ++ss) {
      int px = pxBase + ss * 16;
#pragma unroll
      for (int k = 0; k < 4; ++k) {
        int o = oBase + rr * 16 + k;
        float val = acc[rr][ss][k];
        if (scs) {
          int gx = px & 63;
          val += scs[((size_t)b * COUT + o) * P1 + pxT * 32 + (gx >> 1)] + scb[o];
        }
        Y[((size_t)b * COUT + o) * 4096 + px] = val;
      }
    }
  }
}

extern "C" void kernel_launch(void* const* d_in, const int* in_sizes, int n_in,
                              void* d_out, int out_size, void* d_ws, size_t ws_size,
                              hipStream_t stream) {
  const float* x      = (const float*)d_in[0];
  const float* gcond  = (const float*)d_in[1];
  const float* wemb   = (const float*)d_in[2];
  const int*   mask   = (const int*)d_in[3];
  const float* w_img1 = (const float*)d_in[4];
  const float* w_img2 = (const float*)d_in[5];
  const float* w_c1   = (const float*)d_in[6];
  const float* w_c2   = (const float*)d_in[7];
  const float* bn1_w  = (const float*)d_in[8];
  const float* bn1_b  = (const float*)d_in[9];
  const float* bn2_w  = (const float*)d_in[10];
  const float* bn2_b  = (const float*)d_in[11];
  const float* w_g1   = (const float*)d_in[12];
  const float* b_g1   = (const float*)d_in[13];
  const float* w_b1   = (const float*)d_in[14];
  const float* b_b1   = (const float*)d_in[15];
  const float* w_g2   = (const float*)d_in[16];
  const float* b_g2   = (const float*)d_in[17];
  const float* w_b2   = (const float*)d_in[18];
  const float* b_b2   = (const float*)d_in[19];
  const float* w_sc   = (const float*)d_in[20];
  const float* b_sc   = (const float*)d_in[21];
  float* out = (float*)d_out;
  float* ws = (float*)d_ws;

  const size_t MF = 16777216;  // floats per 64MB region
  float* A  = ws;
  float* Br = ws + MF;
  float* Cr = ws + 2 * MF;
  float* SM = ws + 3 * MF;
  float* wdn   = SM;                     // 131072
  float* attnb = SM + 131072;            // up to 2097152
  float* mean1 = attnb + 2097152;
  float* rstd1 = mean1 + 512;
  float* mean2 = rstd1 + 512;
  float* rstd2 = mean2 + 256;
  float* gvec1 = rstd2 + 256;            // 8192
  float* bvec1 = gvec1 + 8192;
  float* gvec2 = bvec1 + 8192;           // 4096
  float* bvec2 = gvec2 + 4096;
  float* wsp   = bvec2 + 4096;
  u16* Wp1 = (u16*)wsp;                  // 9*256*512 ushorts
  u16* Wp2 = (u16*)(wsp + 655360);       // 9*256*256 ushorts

  float* img1   = A;                     // 4M floats
  float* ctx1   = A + 4194304;           // 4M
  u16*   Xt1    = (u16*)(A + 8388608);   // NHWC bf16, 8.4M u16
  float* gamma1 = Br;                    // 8M
  float* beta1  = Br + 8388608;          // 8M
  float* conv1o = Cr;                    // 16M
  float* img2   = A;                     // reuse
  float* ctx2   = Br;                    // reuse
  float* gamma2 = A;                     // reuse
  float* beta2  = out;                   // d_out as scratch until final conv
  u16*   Xt2    = (u16*)Br;              // reuse (ctx2 dead), 16.8M u16
  float* scs    = Cr;                    // reuse (conv1o dead after act2)

  // ---- stage 1 ----
  bn_stats_kernel<<<dim3(CIN1), dim3(256), 0, stream>>>(x, mean1, rstd1, CIN1, P1);
  wdn_kernel<<<dim3(NB * LL), dim3(64), 0, stream>>>(wemb, wdn);
  pack_w_kernel<<<dim3(COUT * CIN1 / 256), dim3(256), 0, stream>>>(w_c1, Wp1, COUT, CIN1);
  pack_w_kernel<<<dim3(COUT * COUT / 256), dim3(256), 0, stream>>>(w_c2, Wp2, COUT, COUT);
  gemm_wx_kernel<<<dim3(P1 / 64, TD / 64, NB), dim3(256), 0, stream>>>(
      w_img1, CIN1, 0, x, nullptr, img1, TD, CIN1, P1);
  attn_kernel<<<dim3(P1 / 4, NB), dim3(256), 0, stream>>>(img1, wdn, mask, attnb, P1);
  ctx_kernel<<<dim3(P1 / 64, NB), dim3(256), 0, stream>>>(attnb, wdn, ctx1, P1);
  gvec_kernel<<<dim3(CIN1 / 64, NB), dim3(64), 0, stream>>>(w_g1, b_g1, gcond, gvec1, CIN1);
  gvec_kernel<<<dim3(CIN1 / 64, NB), dim3(64), 0, stream>>>(w_b1, b_b1, gcond, bvec1, CIN1);
  gemm_wx_kernel<<<dim3(P1 / 64, CIN1 / 64, NB), dim3(256), 0, stream>>>(
      w_g1, CONDC, GD, ctx1, gvec1, gamma1, CIN1, TD, P1);
  gemm_wx_kernel<<<dim3(P1 / 64, CIN1 / 64, NB), dim3(256), 0, stream>>>(
      w_b1, CONDC, GD, ctx1, bvec1, beta1, CIN1, TD, P1);
  act_nhwc_kernel<<<dim3(P1 / 64, CIN1 / 32, NB), dim3(256), 0, stream>>>(
      x, gamma1, beta1, mean1, rstd1, bn1_w, bn1_b, Xt1, CIN1, P1);
  conv_mfma_kernel<CIN1, true><<<dim3(32, 2, NB), dim3(256), 0, stream>>>(
      Wp1, Xt1, nullptr, nullptr, conv1o);

  // ---- stage 2 ----
  bn_stats_kernel<<<dim3(COUT), dim3(256), 0, stream>>>(conv1o, mean2, rstd2, COUT, P2);
  gemm_wx_kernel<<<dim3(P2 / 64, TD / 64, NB), dim3(256), 0, stream>>>(
      w_img2, COUT, 0, conv1o, nullptr, img2, TD, COUT, P2);
  attn_kernel<<<dim3(P2 / 4, NB), dim3(256), 0, stream>>>(img2, wdn, mask, attnb, P2);
  ctx_kernel<<<dim3(P2 / 64, NB), dim3(256), 0, stream>>>(attnb, wdn, ctx2, P2);
  gvec_kernel<<<dim3(COUT / 64, NB), dim3(64), 0, stream>>>(w_g2, b_g2, gcond, gvec2, COUT);
  gvec_kernel<<<dim3(COUT / 64, NB), dim3(64), 0, stream>>>(w_b2, b_b2, gcond, bvec2, COUT);
  gemm_wx_kernel<<<dim3(P2 / 64, COUT / 64, NB), dim3(256), 0, stream>>>(
      w_g2, CONDC, GD, ctx2, gvec2, gamma2, COUT, TD, P2);
  gemm_wx_kernel<<<dim3(P2 / 64, COUT / 64, NB), dim3(256), 0, stream>>>(
      w_b2, CONDC, GD, ctx2, bvec2, beta2, COUT, TD, P2);
  act_nhwc_kernel<<<dim3(P2 / 64, COUT / 32, NB), dim3(256), 0, stream>>>(
      conv1o, gamma2, beta2, mean2, rstd2, bn2_w, bn2_b, Xt2, COUT, P2);
  gemm_wx_kernel<<<dim3(P1 / 64, COUT / 64, NB), dim3(256), 0, stream>>>(
      w_sc, CIN1, 0, x, nullptr, scs, COUT, CIN1, P1);
  conv_mfma_kernel<COUT, false><<<dim3(32, 2, NB), dim3(256), 0, stream>>>(
      Wp2, Xt2, scs, b_sc, out);
}

// Round 7
// 1014.828 us; speedup vs baseline: 4.2483x; 1.5408x over previous
//
#include <hip/hip_runtime.h>
#include <hip/hip_bf16.h>
#include <math.h>

#define NB 16
#define CIN1 512
#define COUT 256
#define GD 256
#define TD 256
#define LL 32
#define P1 1024
#define P2 4096
#define CONDC 512

typedef __attribute__((ext_vector_type(8))) short bf16x8;
typedef __attribute__((ext_vector_type(4))) float f32x4;
typedef unsigned short u16;

__device__ __forceinline__ u16 f2b(float f) {
  __hip_bfloat16 h = __float2bfloat16(f);
  return *(u16*)&h;
}

// ---------------- BN stats: mean + rsqrt(var+eps) per channel ----------------
__global__ void bn_stats_kernel(const float* __restrict__ x, float* __restrict__ mean,
                                float* __restrict__ rstd, int C, int HW) {
  int c = blockIdx.x, t = threadIdx.x;
  float s = 0.f, sq = 0.f;
  for (int b = 0; b < NB; ++b) {
    const float* p = x + ((size_t)b * C + c) * HW;
    for (int i = t; i < HW; i += 256) { float v = p[i]; s += v; sq += v * v; }
  }
  __shared__ float ss[256], sq2[256];
  ss[t] = s; sq2[t] = sq; __syncthreads();
  for (int o = 128; o > 0; o >>= 1) {
    if (t < o) { ss[t] += ss[t + o]; sq2[t] += sq2[t + o]; }
    __syncthreads();
  }
  if (t == 0) {
    float n = (float)NB * (float)HW;
    float m = ss[0] / n;
    float v = sq2[0] / n - m * m;
    mean[c] = m;
    rstd[c] = rsqrtf(v + 1e-5f);
  }
}

// ---------------- normalize words_embs over channel dim per (b,l) ----------------
__global__ void wdn_kernel(const float* __restrict__ we, float* __restrict__ wdn) {
  int b = blockIdx.x >> 5, l = blockIdx.x & 31;
  int t = threadIdx.x; // 64
  const float* base = we + (size_t)b * TD * LL + l;
  float v[4]; float sq = 0.f;
#pragma unroll
  for (int k = 0; k < 4; ++k) { v[k] = base[(size_t)(t * 4 + k) * LL]; sq += v[k] * v[k]; }
#pragma unroll
  for (int o = 32; o > 0; o >>= 1) sq += __shfl_xor(sq, o);
  float r = 1.f / fmaxf(sqrtf(sq), 1e-12f);
  float* ob = wdn + (size_t)b * TD * LL + l;
#pragma unroll
  for (int k = 0; k < 4; ++k) ob[(size_t)(t * 4 + k) * LL] = v[k] * r;
}

// ---------------- per-pixel: l2norm(img col) -> sim vs wdn -> mask -> softmax ----------------
__global__ __launch_bounds__(256) void attn_kernel(const float* __restrict__ img,
                                                   const float* __restrict__ wdn,
                                                   const int* __restrict__ mask,
                                                   float* __restrict__ attn, int P) {
  __shared__ float imgs[4][TD];
  int wv = threadIdx.x >> 6, lane = threadIdx.x & 63;
  int p = blockIdx.x * 4 + wv, b = blockIdx.y;
  const float* ib = img + (size_t)b * TD * P + p;
  float v[4]; float sq = 0.f;
#pragma unroll
  for (int k = 0; k < 4; ++k) { v[k] = ib[(size_t)(lane * 4 + k) * P]; sq += v[k] * v[k]; }
#pragma unroll
  for (int o = 32; o > 0; o >>= 1) sq += __shfl_xor(sq, o);
  float rn = 1.f / fmaxf(sqrtf(sq), 1e-12f);
  *(float4*)&imgs[wv][lane * 4] = make_float4(v[0], v[1], v[2], v[3]);
  __syncthreads();
  int l = lane & 31, half = lane >> 5;
  const float* wb = wdn + (size_t)b * TD * LL + l;
  float sim = 0.f;
  int c0 = half * 128;
#pragma unroll 8
  for (int c = 0; c < 128; ++c) sim += imgs[wv][c0 + c] * wb[(size_t)(c0 + c) * LL];
  sim += __shfl_xor(sim, 32);
  sim *= rn;
  if (mask[b * LL + l] != 0) sim = -INFINITY;
  float m = sim;
#pragma unroll
  for (int o = 16; o > 0; o >>= 1) m = fmaxf(m, __shfl_xor(m, o));
  float e = expf(sim - m);
  float s = e;
#pragma unroll
  for (int o = 16; o > 0; o >>= 1) s += __shfl_xor(s, o);
  float a = e / s;
  if (half == 0) attn[((size_t)b * P + p) * LL + l] = a;
}

// ---------------- ctx[b,c,p] = sum_l attn[b,p,l]*wdn[b,c,l] ----------------
__global__ __launch_bounds__(256) void ctx_kernel(const float* __restrict__ attn,
                                                  const float* __restrict__ wdn,
                                                  float* __restrict__ ctx, int P) {
  __shared__ float wdns[TD * LL];   // 32 KB
  __shared__ float attns[64 * LL];  // 8 KB
  int b = blockIdx.y, p0 = blockIdx.x * 64, t = threadIdx.x;
  const float4* wsrc = (const float4*)(wdn + (size_t)b * TD * LL);
  for (int i = t; i < TD * LL / 4; i += 256) ((float4*)wdns)[i] = wsrc[i];
  const float4* asrc = (const float4*)(attn + ((size_t)b * P + p0) * LL);
  for (int i = t; i < 64 * LL / 4; i += 256) ((float4*)attns)[i] = asrc[i];
  __syncthreads();
  int pi = t & 63, cg = t >> 6;
  float a[LL];
#pragma unroll
  for (int l = 0; l < LL; l += 4) {
    float4 q = *(float4*)&attns[pi * LL + l];
    a[l] = q.x; a[l + 1] = q.y; a[l + 2] = q.z; a[l + 3] = q.w;
  }
  for (int k = 0; k < 64; ++k) {
    int c = cg * 64 + k;
    float acc = 0.f;
#pragma unroll
    for (int l = 0; l < LL; l += 4) {
      float4 w4 = *(float4*)&wdns[c * LL + l];
      acc += a[l] * w4.x + a[l + 1] * w4.y + a[l + 2] * w4.z + a[l + 3] * w4.w;
    }
    ctx[((size_t)b * TD + c) * P + p0 + pi] = acc;
  }
}

// ---------------- gvec[b,o] = bias[o] + sum_{c<GD} W[o,c]*gc[b,c] ----------------
__global__ void gvec_kernel(const float* __restrict__ Wg, const float* __restrict__ bias,
                            const float* __restrict__ gc, float* __restrict__ outv, int O) {
  int o = blockIdx.x * 64 + threadIdx.x;
  int b = blockIdx.y;
  if (o >= O) return;
  const float* wr = Wg + (size_t)o * CONDC;
  const float* g = gc + (size_t)b * GD;
  float s = 0.f;
  for (int c = 0; c < GD; ++c) s += wr[c] * g[c];
  outv[(size_t)b * O + o] = s + bias[o];
}

// ---------------- bf16 MFMA GEMM: Y[b,t,p] = vec[b,t] + sum_c W[t,c_off+c]*X[b,c,p] ----------------
// Block: 4 waves = 128 t x 128 p. Wave: 4x4 frags of 16x16x32. fp32->bf16 fused in staging.
__global__ __launch_bounds__(256) void gemm_mfma_kernel(
    const float* __restrict__ W, int ldw, int c_off,
    const float* __restrict__ X, const float* __restrict__ vec,
    float* __restrict__ Y, int T, int C, int P) {
  __shared__ u16 Wl[128 * 40];
  __shared__ u16 Xl[128 * 40];
  const int b = blockIdx.z;
  const int t0 = blockIdx.y * 128, p0 = blockIdx.x * 128;
  const int tid = threadIdx.x;
  const int w = tid >> 6, lane = tid & 63;
  const int wo = w >> 1, wq = w & 1;
  const int l15 = lane & 15, lg = lane >> 4;
  const float* Xb = X + (size_t)b * C * P;
  const int wr = tid >> 1, wcH = tid & 1;   // W staging: row, 16-float half
  const int xr = tid >> 3, xcG = tid & 7;   // X staging: c-row, 16-float px group
  f32x4 acc[4][4] = {};

  for (int c0 = 0; c0 < C; c0 += 32) {
    // stage W tile (128 t x 32 c) -> Wl[t][c]
    {
      const float* src = W + (size_t)(t0 + wr) * ldw + c_off + c0 + wcH * 16;
      u16* dst = Wl + wr * 40 + wcH * 16;
#pragma unroll
      for (int j = 0; j < 4; ++j) {
        float4 v = *(const float4*)(src + j * 4);
        ushort4 pk = make_ushort4(f2b(v.x), f2b(v.y), f2b(v.z), f2b(v.w));
        *(ushort4*)(dst + j * 4) = pk;
      }
    }
    // stage X tile (32 c x 128 p) transposed -> Xl[p][c]
    {
      const float* src = Xb + (size_t)(c0 + xr) * P + p0 + xcG * 16;
#pragma unroll
      for (int j = 0; j < 4; ++j) {
        float4 v = *(const float4*)(src + j * 4);
        int px = xcG * 16 + j * 4;
        Xl[(px + 0) * 40 + xr] = f2b(v.x);
        Xl[(px + 1) * 40 + xr] = f2b(v.y);
        Xl[(px + 2) * 40 + xr] = f2b(v.z);
        Xl[(px + 3) * 40 + xr] = f2b(v.w);
      }
    }
    __syncthreads();
    bf16x8 a[4], bb[4];
#pragma unroll
    for (int rr = 0; rr < 4; ++rr)
      a[rr] = *(const bf16x8*)(Wl + (wo * 64 + rr * 16 + l15) * 40 + lg * 8);
#pragma unroll
    for (int ss = 0; ss < 4; ++ss)
      bb[ss] = *(const bf16x8*)(Xl + (wq * 64 + ss * 16 + l15) * 40 + lg * 8);
#pragma unroll
    for (int rr = 0; rr < 4; ++rr)
#pragma unroll
      for (int ss = 0; ss < 4; ++ss)
        acc[rr][ss] = __builtin_amdgcn_mfma_f32_16x16x32_bf16(a[rr], bb[ss], acc[rr][ss], 0, 0, 0);
    __syncthreads();
  }
  // epilogue: C/D frag: col(p)=lane&15, row(t)=lg*4+k
#pragma unroll
  for (int rr = 0; rr < 4; ++rr) {
    int tb = t0 + wo * 64 + rr * 16 + lg * 4;
#pragma unroll
    for (int ss = 0; ss < 4; ++ss) {
      int p = p0 + wq * 64 + ss * 16 + l15;
#pragma unroll
      for (int k = 0; k < 4; ++k) {
        int t = tb + k;
        float val = acc[rr][ss][k];
        if (vec) val += vec[(size_t)b * T + t];
        Y[((size_t)b * T + t) * P + p] = val;
      }
    }
  }
}

// ---------------- fused: relu(gamma*BN(x)+beta) -> NHWC bf16 (LDS transpose) ----------------
__global__ __launch_bounds__(256) void act_nhwc_kernel(
    const float* __restrict__ xin, const float* __restrict__ gamma,
    const float* __restrict__ beta, const float* __restrict__ mean,
    const float* __restrict__ rstd, const float* __restrict__ bnw,
    const float* __restrict__ bnb, u16* __restrict__ outb, int C, int P) {
  __shared__ u16 Ts[32][68];
  int b = blockIdx.z, c0 = blockIdx.y * 32, p0 = blockIdx.x * 64;
  int tid = threadIdx.x;
  { // phase 1: compute 32c x 64px tile, rows coalesced
    int cr = tid >> 3, pg = tid & 7;
    int c = c0 + cr;
    size_t base = ((size_t)b * C + c) * P + p0 + pg * 8;
    float m = mean[c], r = rstd[c] * bnw[c], bb = bnb[c];
    float4 x1 = *(const float4*)(xin + base), x2 = *(const float4*)(xin + base + 4);
    float4 g1 = *(const float4*)(gamma + base), g2 = *(const float4*)(gamma + base + 4);
    float4 t1 = *(const float4*)(beta + base), t2 = *(const float4*)(beta + base + 4);
    float xv[8] = {x1.x, x1.y, x1.z, x1.w, x2.x, x2.y, x2.z, x2.w};
    float gv[8] = {g1.x, g1.y, g1.z, g1.w, g2.x, g2.y, g2.z, g2.w};
    float bv[8] = {t1.x, t1.y, t1.z, t1.w, t2.x, t2.y, t2.z, t2.w};
#pragma unroll
    for (int j = 0; j < 8; ++j) {
      float o = fmaxf(gv[j] * ((xv[j] - m) * r + bb) + bv[j], 0.f);
      Ts[cr][pg * 8 + j] = f2b(o);
    }
  }
  __syncthreads();
  { // phase 2: write NHWC, c contiguous
    int pr = tid >> 2, cg = tid & 3;
    union { u16 u[8]; uint4 v; } pk;
#pragma unroll
    for (int j = 0; j < 8; ++j) pk.u[j] = Ts[cg * 8 + j][pr];
    *(uint4*)(outb + ((size_t)b * P + p0 + pr) * C + c0 + cg * 8) = pk.v;
  }
}

// ---------------- pack conv weights: w[o][c][3][3] fp32 -> fragment-linear bf16 ----------------
// Wf[pos][c0blk][ot][lane=lg*16+l15][8c]  (wave A-load = 1KB contiguous)
__global__ void pack_w_kernel(const float* __restrict__ w, u16* __restrict__ wp, int O, int CIN) {
  int lin = blockIdx.x * 256 + threadIdx.x;
  if (lin >= O * CIN) return;
  int o = lin / CIN, c = lin - o * CIN;
  int c0blk = c >> 5, lg = (c >> 3) & 3, cc = c & 7;
  int ot = o >> 4, l15 = o & 15;
  int lane = lg * 16 + l15;
  size_t base = (((size_t)c0blk * (O >> 4) + ot) * 64 + lane) * 8 + cc;
  size_t posStride = (size_t)(CIN >> 5) * (O >> 4) * 512;
  const float* src = w + (size_t)lin * 9;
#pragma unroll
  for (int pos = 0; pos < 9; ++pos)
    wp[pos * posStride + base] = f2b(src[pos]);
}

// ---------------- bf16 MFMA implicit-GEMM 3x3 conv ----------------
template <int CIN, bool UP>
__global__ __launch_bounds__(256) void conv_mfma_kernel(
    const u16* __restrict__ Wp, const u16* __restrict__ Xt,
    const float* __restrict__ scs, const float* __restrict__ scb,
    float* __restrict__ Y) {
  constexpr int S = UP ? 32 : 64;
  constexpr int NC0 = CIN >> 5;
  __shared__ u16 Xs[4 * 66 * 36];  // 4 rows x 66 cols x (32c + 4 pad)
  const int b = blockIdx.z, oT = blockIdx.y, pxT = blockIdx.x;
  const int tid = threadIdx.x;
  const int w = tid >> 6, lane = tid & 63;
  const int wo = w >> 1, wp = w & 1;
  const int l15 = lane & 15, lg = lane >> 4;
  const int Y0 = pxT * 2;
  const u16* Xb = Xt + (size_t)b * S * S * CIN;
  f32x4 acc[4][4] = {};

  for (int c0b = 0; c0b < NC0; ++c0b) {
    const int c0 = c0b << 5;
    // stage input window: rows Y0-1..Y0+2, cols -1..64, channels c0..c0+31
    for (int i = tid; i < 2112; i += 256) {
      int r = i / 528;
      int rem = i - r * 528;
      int col = rem >> 3;
      int ch = rem & 7;
      int uy = Y0 - 1 + r, ux = col - 1;
      uint2 v = make_uint2(0u, 0u);
      if (uy >= 0 && uy < 64 && ux >= 0 && ux < 64) {
        int sy = UP ? (uy >> 1) : uy, sx = UP ? (ux >> 1) : ux;
        v = *(const uint2*)(Xb + ((size_t)sy * S + sx) * CIN + c0 + ch * 4);
      }
      *(uint2*)(Xs + (r * 66 + col) * 36 + ch * 4) = v;
    }
    __syncthreads();
#pragma unroll
    for (int ky = 0; ky < 3; ++ky) {
#pragma unroll
      for (int kx = 0; kx < 3; ++kx) {
        const int pos = ky * 3 + kx;
        // fragment-linear weights: wave reads 1KB contiguous
        const u16* wb = Wp + (((size_t)pos * NC0 + c0b) * 16 + oT * 8 + wo * 4) * 512 + lane * 8;
        bf16x8 a[4], bfr[4];
#pragma unroll
        for (int rr = 0; rr < 4; ++rr)
          a[rr] = *(const bf16x8*)(wb + rr * 512);
        const int rowb = ((wp + ky) * 66 + kx) * 36 + lg * 8;
#pragma unroll
        for (int ss = 0; ss < 4; ++ss) {
          int idx = rowb + (ss * 16 + l15) * 36;
          union { uint2 q[2]; bf16x8 v; } u;
          u.q[0] = *(const uint2*)(Xs + idx);
          u.q[1] = *(const uint2*)(Xs + idx + 4);
          bfr[ss] = u.v;
        }
#pragma unroll
        for (int rr = 0; rr < 4; ++rr)
#pragma unroll
          for (int ss = 0; ss < 4; ++ss)
            acc[rr][ss] = __builtin_amdgcn_mfma_f32_16x16x32_bf16(a[rr], bfr[ss], acc[rr][ss], 0, 0, 0);
      }
    }
    __syncthreads();
  }
  const int oBase = oT * 128 + wo * 64 + lg * 4;
  const int pxBase = pxT * 128 + wp * 64 + l15;
#pragma unroll
  for (int rr = 0; rr < 4; ++rr) {
#pragma unroll
    for (int ss = 0; ss < 4; ++ss) {
      int px = pxBase + ss * 16;
#pragma unroll
      for (int k = 0; k < 4; ++k) {
        int o = oBase + rr * 16 + k;
        float val = acc[rr][ss][k];
        if (scs) {
          int gx = px & 63;
          val += scs[((size_t)b * COUT + o) * P1 + pxT * 32 + (gx >> 1)] + scb[o];
        }
        Y[((size_t)b * COUT + o) * 4096 + px] = val;
      }
    }
  }
}

extern "C" void kernel_launch(void* const* d_in, const int* in_sizes, int n_in,
                              void* d_out, int out_size, void* d_ws, size_t ws_size,
                              hipStream_t stream) {
  const float* x      = (const float*)d_in[0];
  const float* gcond  = (const float*)d_in[1];
  const float* wemb   = (const float*)d_in[2];
  const int*   mask   = (const int*)d_in[3];
  const float* w_img1 = (const float*)d_in[4];
  const float* w_img2 = (const float*)d_in[5];
  const float* w_c1   = (const float*)d_in[6];
  const float* w_c2   = (const float*)d_in[7];
  const float* bn1_w  = (const float*)d_in[8];
  const float* bn1_b  = (const float*)d_in[9];
  const float* bn2_w  = (const float*)d_in[10];
  const float* bn2_b  = (const float*)d_in[11];
  const float* w_g1   = (const float*)d_in[12];
  const float* b_g1   = (const float*)d_in[13];
  const float* w_b1   = (const float*)d_in[14];
  const float* b_b1   = (const float*)d_in[15];
  const float* w_g2   = (const float*)d_in[16];
  const float* b_g2   = (const float*)d_in[17];
  const float* w_b2   = (const float*)d_in[18];
  const float* b_b2   = (const float*)d_in[19];
  const float* w_sc   = (const float*)d_in[20];
  const float* b_sc   = (const float*)d_in[21];
  float* out = (float*)d_out;
  float* ws = (float*)d_ws;

  const size_t MF = 16777216;  // floats per 64MB region
  float* A  = ws;
  float* Br = ws + MF;
  float* Cr = ws + 2 * MF;
  float* SM = ws + 3 * MF;
  float* wdn   = SM;                     // 131072
  float* attnb = SM + 131072;            // up to 2097152
  float* mean1 = attnb + 2097152;
  float* rstd1 = mean1 + 512;
  float* mean2 = rstd1 + 512;
  float* rstd2 = mean2 + 256;
  float* gvec1 = rstd2 + 256;            // 8192
  float* bvec1 = gvec1 + 8192;
  float* gvec2 = bvec1 + 8192;           // 4096
  float* bvec2 = gvec2 + 4096;
  float* wsp   = bvec2 + 4096;
  u16* Wp1 = (u16*)wsp;                  // 9*256*512 ushorts
  u16* Wp2 = (u16*)(wsp + 655360);       // 9*256*256 ushorts

  float* img1   = A;                     // 4M floats
  float* ctx1   = A + 4194304;           // 4M
  u16*   Xt1    = (u16*)(A + 8388608);   // NHWC bf16
  float* gamma1 = Br;                    // 8M
  float* beta1  = Br + 8388608;          // 8M
  float* conv1o = Cr;                    // 16M
  float* img2   = A;                     // reuse
  float* ctx2   = Br;                    // reuse
  float* gamma2 = A;                     // reuse
  float* beta2  = out;                   // d_out as scratch until final conv
  u16*   Xt2    = (u16*)Br;              // reuse (ctx2 dead)
  float* scs    = Cr;                    // reuse (conv1o dead after act2)

  // ---- stage 1 ----
  bn_stats_kernel<<<dim3(CIN1), dim3(256), 0, stream>>>(x, mean1, rstd1, CIN1, P1);
  wdn_kernel<<<dim3(NB * LL), dim3(64), 0, stream>>>(wemb, wdn);
  pack_w_kernel<<<dim3(COUT * CIN1 / 256), dim3(256), 0, stream>>>(w_c1, Wp1, COUT, CIN1);
  pack_w_kernel<<<dim3(COUT * COUT / 256), dim3(256), 0, stream>>>(w_c2, Wp2, COUT, COUT);
  gemm_mfma_kernel<<<dim3(P1 / 128, TD / 128, NB), dim3(256), 0, stream>>>(
      w_img1, CIN1, 0, x, nullptr, img1, TD, CIN1, P1);
  attn_kernel<<<dim3(P1 / 4, NB), dim3(256), 0, stream>>>(img1, wdn, mask, attnb, P1);
  ctx_kernel<<<dim3(P1 / 64, NB), dim3(256), 0, stream>>>(attnb, wdn, ctx1, P1);
  gvec_kernel<<<dim3(CIN1 / 64, NB), dim3(64), 0, stream>>>(w_g1, b_g1, gcond, gvec1, CIN1);
  gvec_kernel<<<dim3(CIN1 / 64, NB), dim3(64), 0, stream>>>(w_b1, b_b1, gcond, bvec1, CIN1);
  gemm_mfma_kernel<<<dim3(P1 / 128, CIN1 / 128, NB), dim3(256), 0, stream>>>(
      w_g1, CONDC, GD, ctx1, gvec1, gamma1, CIN1, TD, P1);
  gemm_mfma_kernel<<<dim3(P1 / 128, CIN1 / 128, NB), dim3(256), 0, stream>>>(
      w_b1, CONDC, GD, ctx1, bvec1, beta1, CIN1, TD, P1);
  act_nhwc_kernel<<<dim3(P1 / 64, CIN1 / 32, NB), dim3(256), 0, stream>>>(
      x, gamma1, beta1, mean1, rstd1, bn1_w, bn1_b, Xt1, CIN1, P1);
  conv_mfma_kernel<CIN1, true><<<dim3(32, 2, NB), dim3(256), 0, stream>>>(
      Wp1, Xt1, nullptr, nullptr, conv1o);

  // ---- stage 2 ----
  bn_stats_kernel<<<dim3(COUT), dim3(256), 0, stream>>>(conv1o, mean2, rstd2, COUT, P2);
  gemm_mfma_kernel<<<dim3(P2 / 128, TD / 128, NB), dim3(256), 0, stream>>>(
      w_img2, COUT, 0, conv1o, nullptr, img2, TD, COUT, P2);
  attn_kernel<<<dim3(P2 / 4, NB), dim3(256), 0, stream>>>(img2, wdn, mask, attnb, P2);
  ctx_kernel<<<dim3(P2 / 64, NB), dim3(256), 0, stream>>>(attnb, wdn, ctx2, P2);
  gvec_kernel<<<dim3(COUT / 64, NB), dim3(64), 0, stream>>>(w_g2, b_g2, gcond, gvec2, COUT);
  gvec_kernel<<<dim3(COUT / 64, NB), dim3(64), 0, stream>>>(w_b2, b_b2, gcond, bvec2, COUT);
  gemm_mfma_kernel<<<dim3(P2 / 128, COUT / 128, NB), dim3(256), 0, stream>>>(
      w_g2, CONDC, GD, ctx2, gvec2, gamma2, COUT, TD, P2);
  gemm_mfma_kernel<<<dim3(P2 / 128, COUT / 128, NB), dim3(256), 0, stream>>>(
      w_b2, CONDC, GD, ctx2, bvec2, beta2, COUT, TD, P2);
  act_nhwc_kernel<<<dim3(P2 / 64, COUT / 32, NB), dim3(256), 0, stream>>>(
      conv1o, gamma2, beta2, mean2, rstd2, bn2_w, bn2_b, Xt2, COUT, P2);
  gemm_mfma_kernel<<<dim3(P1 / 128, COUT / 128, NB), dim3(256), 0, stream>>>(
      w_sc, CIN1, 0, x, nullptr, scs, COUT, CIN1, P1);
  conv_mfma_kernel<COUT, false><<<dim3(32, 2, NB), dim3(256), 0, stream>>>(
      Wp2, Xt2, scs, b_sc, out);
}

// Round 8
// 969.552 us; speedup vs baseline: 4.4467x; 1.0467x over previous
//
#include <hip/hip_runtime.h>
#include <hip/hip_bf16.h>
#include <math.h>

#define NB 16
#define CIN1 512
#define COUT 256
#define GD 256
#define TD 256
#define LL 32
#define P1 1024
#define P2 4096
#define CONDC 512

typedef __attribute__((ext_vector_type(8))) short bf16x8;
typedef __attribute__((ext_vector_type(4))) float f32x4;
typedef unsigned short u16;

__device__ __forceinline__ u16 f2b(float f) {
  __hip_bfloat16 h = __float2bfloat16(f);
  return *(u16*)&h;
}

// ---------------- BN stats: mean + rsqrt(var+eps) per channel ----------------
__global__ void bn_stats_kernel(const float* __restrict__ x, float* __restrict__ mean,
                                float* __restrict__ rstd, int C, int HW) {
  int c = blockIdx.x, t = threadIdx.x;
  float s = 0.f, sq = 0.f;
  for (int b = 0; b < NB; ++b) {
    const float* p = x + ((size_t)b * C + c) * HW;
    for (int i = t; i < HW; i += 256) { float v = p[i]; s += v; sq += v * v; }
  }
  __shared__ float ss[256], sq2[256];
  ss[t] = s; sq2[t] = sq; __syncthreads();
  for (int o = 128; o > 0; o >>= 1) {
    if (t < o) { ss[t] += ss[t + o]; sq2[t] += sq2[t + o]; }
    __syncthreads();
  }
  if (t == 0) {
    float n = (float)NB * (float)HW;
    float m = ss[0] / n;
    float v = sq2[0] / n - m * m;
    mean[c] = m;
    rstd[c] = rsqrtf(v + 1e-5f);
  }
}

// ---------------- normalize words_embs over channel dim per (b,l) ----------------
__global__ void wdn_kernel(const float* __restrict__ we, float* __restrict__ wdn) {
  int b = blockIdx.x >> 5, l = blockIdx.x & 31;
  int t = threadIdx.x; // 64
  const float* base = we + (size_t)b * TD * LL + l;
  float v[4]; float sq = 0.f;
#pragma unroll
  for (int k = 0; k < 4; ++k) { v[k] = base[(size_t)(t * 4 + k) * LL]; sq += v[k] * v[k]; }
#pragma unroll
  for (int o = 32; o > 0; o >>= 1) sq += __shfl_xor(sq, o);
  float r = 1.f / fmaxf(sqrtf(sq), 1e-12f);
  float* ob = wdn + (size_t)b * TD * LL + l;
#pragma unroll
  for (int k = 0; k < 4; ++k) ob[(size_t)(t * 4 + k) * LL] = v[k] * r;
}

// ---------------- per-pixel: l2norm(img col) -> sim vs wdn -> mask -> softmax ----------------
__global__ __launch_bounds__(256) void attn_kernel(const float* __restrict__ img,
                                                   const float* __restrict__ wdn,
                                                   const int* __restrict__ mask,
                                                   float* __restrict__ attn, int P) {
  __shared__ float imgs[4][TD];
  int wv = threadIdx.x >> 6, lane = threadIdx.x & 63;
  int p = blockIdx.x * 4 + wv, b = blockIdx.y;
  const float* ib = img + (size_t)b * TD * P + p;
  float v[4]; float sq = 0.f;
#pragma unroll
  for (int k = 0; k < 4; ++k) { v[k] = ib[(size_t)(lane * 4 + k) * P]; sq += v[k] * v[k]; }
#pragma unroll
  for (int o = 32; o > 0; o >>= 1) sq += __shfl_xor(sq, o);
  float rn = 1.f / fmaxf(sqrtf(sq), 1e-12f);
  *(float4*)&imgs[wv][lane * 4] = make_float4(v[0], v[1], v[2], v[3]);
  __syncthreads();
  int l = lane & 31, half = lane >> 5;
  const float* wb = wdn + (size_t)b * TD * LL + l;
  float sim = 0.f;
  int c0 = half * 128;
#pragma unroll 8
  for (int c = 0; c < 128; ++c) sim += imgs[wv][c0 + c] * wb[(size_t)(c0 + c) * LL];
  sim += __shfl_xor(sim, 32);
  sim *= rn;
  if (mask[b * LL + l] != 0) sim = -INFINITY;
  float m = sim;
#pragma unroll
  for (int o = 16; o > 0; o >>= 1) m = fmaxf(m, __shfl_xor(m, o));
  float e = expf(sim - m);
  float s = e;
#pragma unroll
  for (int o = 16; o > 0; o >>= 1) s += __shfl_xor(s, o);
  float a = e / s;
  if (half == 0) attn[((size_t)b * P + p) * LL + l] = a;
}

// ---------------- ctx[b,c,p] = sum_l attn[b,p,l]*wdn[b,c,l] ----------------
__global__ __launch_bounds__(256) void ctx_kernel(const float* __restrict__ attn,
                                                  const float* __restrict__ wdn,
                                                  float* __restrict__ ctx, int P) {
  __shared__ float wdns[TD * LL];   // 32 KB
  __shared__ float attns[64 * LL];  // 8 KB
  int b = blockIdx.y, p0 = blockIdx.x * 64, t = threadIdx.x;
  const float4* wsrc = (const float4*)(wdn + (size_t)b * TD * LL);
  for (int i = t; i < TD * LL / 4; i += 256) ((float4*)wdns)[i] = wsrc[i];
  const float4* asrc = (const float4*)(attn + ((size_t)b * P + p0) * LL);
  for (int i = t; i < 64 * LL / 4; i += 256) ((float4*)attns)[i] = asrc[i];
  __syncthreads();
  int pi = t & 63, cg = t >> 6;
  float a[LL];
#pragma unroll
  for (int l = 0; l < LL; l += 4) {
    float4 q = *(float4*)&attns[pi * LL + l];
    a[l] = q.x; a[l + 1] = q.y; a[l + 2] = q.z; a[l + 3] = q.w;
  }
  for (int k = 0; k < 64; ++k) {
    int c = cg * 64 + k;
    float acc = 0.f;
#pragma unroll
    for (int l = 0; l < LL; l += 4) {
      float4 w4 = *(float4*)&wdns[c * LL + l];
      acc += a[l] * w4.x + a[l + 1] * w4.y + a[l + 2] * w4.z + a[l + 3] * w4.w;
    }
    ctx[((size_t)b * TD + c) * P + p0 + pi] = acc;
  }
}

// ---------------- gvec[b,o] = bias[o] + sum_{c<GD} W[o,c]*gc[b,c] ----------------
__global__ void gvec_kernel(const float* __restrict__ Wg, const float* __restrict__ bias,
                            const float* __restrict__ gc, float* __restrict__ outv, int O) {
  int o = blockIdx.x * 64 + threadIdx.x;
  int b = blockIdx.y;
  if (o >= O) return;
  const float* wr = Wg + (size_t)o * CONDC;
  const float* g = gc + (size_t)b * GD;
  float s = 0.f;
  for (int c = 0; c < GD; ++c) s += wr[c] * g[c];
  outv[(size_t)b * O + o] = s + bias[o];
}

// ---------------- bf16 MFMA GEMM: Y[b,t,p] = vec[b,t] + sum_c W[t,c_off+c]*X[b,c,p] ----------------
// Block: 4 waves = 128 t x 128 p. Wave: 4x4 frags of 16x16x32. fp32->bf16 fused in staging.
// Xl uses XOR swizzle on c-blocks (block' = block ^ ((px>>4)&3)) to kill 16-way write conflicts.
// Wl row stride 44 u16 (conflict-free reads, 2-way writes).
__global__ __launch_bounds__(256) void gemm_mfma_kernel(
    const float* __restrict__ W, int ldw, int c_off,
    const float* __restrict__ X, const float* __restrict__ vec,
    float* __restrict__ Y, int T, int C, int P) {
  __shared__ u16 Wl[128 * 44];
  __shared__ u16 Xl[128 * 40];
  const int b = blockIdx.z;
  const int t0 = blockIdx.y * 128, p0 = blockIdx.x * 128;
  const int tid = threadIdx.x;
  const int w = tid >> 6, lane = tid & 63;
  const int wo = w >> 1, wq = w & 1;
  const int l15 = lane & 15, lg = lane >> 4;
  const float* Xb = X + (size_t)b * C * P;
  const int wr = tid >> 1, wcH = tid & 1;   // W staging: row, 16-float half
  const int xr = tid >> 3, xcG = tid & 7;   // X staging: c-row, 16-float px group
  const int csw = xr ^ ((xcG & 3) << 3);    // swizzled c position for X writes
  f32x4 acc[4][4] = {};

  for (int c0 = 0; c0 < C; c0 += 32) {
    // stage W tile (128 t x 32 c) -> Wl[t][c], stride 44
    {
      const float* src = W + (size_t)(t0 + wr) * ldw + c_off + c0 + wcH * 16;
      u16* dst = Wl + wr * 44 + wcH * 16;
#pragma unroll
      for (int j = 0; j < 4; ++j) {
        float4 v = *(const float4*)(src + j * 4);
        ushort4 pk = make_ushort4(f2b(v.x), f2b(v.y), f2b(v.z), f2b(v.w));
        *(ushort4*)(dst + j * 4) = pk;
      }
    }
    // stage X tile (32 c x 128 p) transposed -> Xl[p][c-swizzled], stride 40
    {
      const float* src = Xb + (size_t)(c0 + xr) * P + p0 + xcG * 16;
#pragma unroll
      for (int j = 0; j < 4; ++j) {
        float4 v = *(const float4*)(src + j * 4);
        int px = xcG * 16 + j * 4;
        Xl[(px + 0) * 40 + csw] = f2b(v.x);
        Xl[(px + 1) * 40 + csw] = f2b(v.y);
        Xl[(px + 2) * 40 + csw] = f2b(v.z);
        Xl[(px + 3) * 40 + csw] = f2b(v.w);
      }
    }
    __syncthreads();
    bf16x8 a[4], bb[4];
#pragma unroll
    for (int rr = 0; rr < 4; ++rr)
      a[rr] = *(const bf16x8*)(Wl + (wo * 64 + rr * 16 + l15) * 44 + lg * 8);
#pragma unroll
    for (int ss = 0; ss < 4; ++ss)
      bb[ss] = *(const bf16x8*)(Xl + (wq * 64 + ss * 16 + l15) * 40 + ((lg ^ ss) << 3));
#pragma unroll
    for (int rr = 0; rr < 4; ++rr)
#pragma unroll
      for (int ss = 0; ss < 4; ++ss)
        acc[rr][ss] = __builtin_amdgcn_mfma_f32_16x16x32_bf16(a[rr], bb[ss], acc[rr][ss], 0, 0, 0);
    __syncthreads();
  }
  // epilogue: C/D frag: col(p)=lane&15, row(t)=lg*4+k
#pragma unroll
  for (int rr = 0; rr < 4; ++rr) {
    int tb = t0 + wo * 64 + rr * 16 + lg * 4;
#pragma unroll
    for (int ss = 0; ss < 4; ++ss) {
      int p = p0 + wq * 64 + ss * 16 + l15;
#pragma unroll
      for (int k = 0; k < 4; ++k) {
        int t = tb + k;
        float val = acc[rr][ss][k];
        if (vec) val += vec[(size_t)b * T + t];
        Y[((size_t)b * T + t) * P + p] = val;
      }
    }
  }
}

// ---------------- fused: relu(gamma*BN(x)+beta) -> NHWC bf16 (LDS transpose) ----------------
__global__ __launch_bounds__(256) void act_nhwc_kernel(
    const float* __restrict__ xin, const float* __restrict__ gamma,
    const float* __restrict__ beta, const float* __restrict__ mean,
    const float* __restrict__ rstd, const float* __restrict__ bnw,
    const float* __restrict__ bnb, u16* __restrict__ outb, int C, int P) {
  __shared__ u16 Ts[32][68];
  int b = blockIdx.z, c0 = blockIdx.y * 32, p0 = blockIdx.x * 64;
  int tid = threadIdx.x;
  { // phase 1: compute 32c x 64px tile, rows coalesced
    int cr = tid >> 3, pg = tid & 7;
    int c = c0 + cr;
    size_t base = ((size_t)b * C + c) * P + p0 + pg * 8;
    float m = mean[c], r = rstd[c] * bnw[c], bb = bnb[c];
    float4 x1 = *(const float4*)(xin + base), x2 = *(const float4*)(xin + base + 4);
    float4 g1 = *(const float4*)(gamma + base), g2 = *(const float4*)(gamma + base + 4);
    float4 t1 = *(const float4*)(beta + base), t2 = *(const float4*)(beta + base + 4);
    float xv[8] = {x1.x, x1.y, x1.z, x1.w, x2.x, x2.y, x2.z, x2.w};
    float gv[8] = {g1.x, g1.y, g1.z, g1.w, g2.x, g2.y, g2.z, g2.w};
    float bv[8] = {t1.x, t1.y, t1.z, t1.w, t2.x, t2.y, t2.z, t2.w};
#pragma unroll
    for (int j = 0; j < 8; ++j) {
      float o = fmaxf(gv[j] * ((xv[j] - m) * r + bb) + bv[j], 0.f);
      Ts[cr][pg * 8 + j] = f2b(o);
    }
  }
  __syncthreads();
  { // phase 2: write NHWC, c contiguous
    int pr = tid >> 2, cg = tid & 3;
    union { u16 u[8]; uint4 v; } pk;
#pragma unroll
    for (int j = 0; j < 8; ++j) pk.u[j] = Ts[cg * 8 + j][pr];
    *(uint4*)(outb + ((size_t)b * P + p0 + pr) * C + c0 + cg * 8) = pk.v;
  }
}

// ---------------- pack conv weights: w[o][c][3][3] fp32 -> fragment-linear bf16 ----------------
// Wf[pos][c0blk][ot][lane=lg*16+l15][8c]  (wave A-load = 1KB contiguous)
__global__ void pack_w_kernel(const float* __restrict__ w, u16* __restrict__ wp, int O, int CIN) {
  int lin = blockIdx.x * 256 + threadIdx.x;
  if (lin >= O * CIN) return;
  int o = lin / CIN, c = lin - o * CIN;
  int c0blk = c >> 5, lg = (c >> 3) & 3, cc = c & 7;
  int ot = o >> 4, l15 = o & 15;
  int lane = lg * 16 + l15;
  size_t base = (((size_t)c0blk * (O >> 4) + ot) * 64 + lane) * 8 + cc;
  size_t posStride = (size_t)(CIN >> 5) * (O >> 4) * 512;
  const float* src = w + (size_t)lin * 9;
#pragma unroll
  for (int pos = 0; pos < 9; ++pos)
    wp[pos * posStride + base] = f2b(src[pos]);
}

// ---------------- bf16 MFMA implicit-GEMM 3x3 conv (double-buffered, early-issue staging) ----------------
template <int CIN, bool UP>
__global__ __launch_bounds__(256) void conv_mfma_kernel(
    const u16* __restrict__ Wp, const u16* __restrict__ Xt,
    const float* __restrict__ scs, const float* __restrict__ scb,
    float* __restrict__ Y) {
  constexpr int S = UP ? 32 : 64;
  constexpr int NC0 = CIN >> 5;
  __shared__ u16 Xs[2][4 * 66 * 36];  // double buffer, 19008 B each
  const int b = blockIdx.z, oT = blockIdx.y, pxT = blockIdx.x;
  const int tid = threadIdx.x;
  const int w = tid >> 6, lane = tid & 63;
  const int wo = w >> 1, wp_ = w & 1;
  const int l15 = lane & 15, lg = lane >> 4;
  const int Y0 = pxT * 2;
  const u16* Xb = Xt + (size_t)b * S * S * CIN;
  f32x4 acc[4][4] = {};
  uint2 st[9];

  // prologue: load + write tile 0
#pragma unroll
  for (int j = 0; j < 9; ++j) {
    int i = tid + j * 256;
    if (i < 2112) {
      int r = i / 528, rem = i - r * 528, col = rem >> 3, ch = rem & 7;
      int uy = Y0 - 1 + r, ux = col - 1;
      uint2 v = make_uint2(0u, 0u);
      if (uy >= 0 && uy < 64 && ux >= 0 && ux < 64) {
        int sy = UP ? (uy >> 1) : uy, sx = UP ? (ux >> 1) : ux;
        v = *(const uint2*)(Xb + ((size_t)sy * S + sx) * CIN + ch * 4);
      }
      st[j] = v;
    }
  }
#pragma unroll
  for (int j = 0; j < 9; ++j) {
    int i = tid + j * 256;
    if (i < 2112) {
      int r = i / 528, rem = i - r * 528, col = rem >> 3, ch = rem & 7;
      *(uint2*)(&Xs[0][(r * 66 + col) * 36 + ch * 4]) = st[j];
    }
  }
  __syncthreads();

  for (int c0b = 0; c0b < NC0; ++c0b) {
    const int cur = c0b & 1;
    // early-issue loads for next tile (land during compute)
    if (c0b + 1 < NC0) {
      const int c0n = (c0b + 1) << 5;
#pragma unroll
      for (int j = 0; j < 9; ++j) {
        int i = tid + j * 256;
        if (i < 2112) {
          int r = i / 528, rem = i - r * 528, col = rem >> 3, ch = rem & 7;
          int uy = Y0 - 1 + r, ux = col - 1;
          uint2 v = make_uint2(0u, 0u);
          if (uy >= 0 && uy < 64 && ux >= 0 && ux < 64) {
            int sy = UP ? (uy >> 1) : uy, sx = UP ? (ux >> 1) : ux;
            v = *(const uint2*)(Xb + ((size_t)sy * S + sx) * CIN + c0n + ch * 4);
          }
          st[j] = v;
        }
      }
    }
    // compute on current buffer
#pragma unroll
    for (int ky = 0; ky < 3; ++ky) {
#pragma unroll
      for (int kx = 0; kx < 3; ++kx) {
        const int pos = ky * 3 + kx;
        const u16* wb = Wp + (((size_t)pos * NC0 + c0b) * 16 + oT * 8 + wo * 4) * 512 + lane * 8;
        bf16x8 a[4], bfr[4];
#pragma unroll
        for (int rr = 0; rr < 4; ++rr)
          a[rr] = *(const bf16x8*)(wb + rr * 512);
        const int rowb = ((wp_ + ky) * 66 + kx) * 36 + lg * 8;
#pragma unroll
        for (int ss = 0; ss < 4; ++ss) {
          int idx = rowb + (ss * 16 + l15) * 36;
          union { uint2 q[2]; bf16x8 v; } u;
          u.q[0] = *(const uint2*)(&Xs[cur][idx]);
          u.q[1] = *(const uint2*)(&Xs[cur][idx + 4]);
          bfr[ss] = u.v;
        }
#pragma unroll
        for (int rr = 0; rr < 4; ++rr)
#pragma unroll
          for (int ss = 0; ss < 4; ++ss)
            acc[rr][ss] = __builtin_amdgcn_mfma_f32_16x16x32_bf16(a[rr], bfr[ss], acc[rr][ss], 0, 0, 0);
      }
    }
    // write next tile into the other buffer; single barrier per iter
    if (c0b + 1 < NC0) {
#pragma unroll
      for (int j = 0; j < 9; ++j) {
        int i = tid + j * 256;
        if (i < 2112) {
          int r = i / 528, rem = i - r * 528, col = rem >> 3, ch = rem & 7;
          *(uint2*)(&Xs[cur ^ 1][(r * 66 + col) * 36 + ch * 4]) = st[j];
        }
      }
      __syncthreads();
    }
  }
  const int oBase = oT * 128 + wo * 64 + lg * 4;
  const int pxBase = pxT * 128 + wp_ * 64 + l15;
#pragma unroll
  for (int rr = 0; rr < 4; ++rr) {
#pragma unroll
    for (int ss = 0; ss < 4; ++ss) {
      int px = pxBase + ss * 16;
#pragma unroll
      for (int k = 0; k < 4; ++k) {
        int o = oBase + rr * 16 + k;
        float val = acc[rr][ss][k];
        if (scs) {
          int gx = px & 63;
          val += scs[((size_t)b * COUT + o) * P1 + pxT * 32 + (gx >> 1)] + scb[o];
        }
        Y[((size_t)b * COUT + o) * 4096 + px] = val;
      }
    }
  }
}

extern "C" void kernel_launch(void* const* d_in, const int* in_sizes, int n_in,
                              void* d_out, int out_size, void* d_ws, size_t ws_size,
                              hipStream_t stream) {
  const float* x      = (const float*)d_in[0];
  const float* gcond  = (const float*)d_in[1];
  const float* wemb   = (const float*)d_in[2];
  const int*   mask   = (const int*)d_in[3];
  const float* w_img1 = (const float*)d_in[4];
  const float* w_img2 = (const float*)d_in[5];
  const float* w_c1   = (const float*)d_in[6];
  const float* w_c2   = (const float*)d_in[7];
  const float* bn1_w  = (const float*)d_in[8];
  const float* bn1_b  = (const float*)d_in[9];
  const float* bn2_w  = (const float*)d_in[10];
  const float* bn2_b  = (const float*)d_in[11];
  const float* w_g1   = (const float*)d_in[12];
  const float* b_g1   = (const float*)d_in[13];
  const float* w_b1   = (const float*)d_in[14];
  const float* b_b1   = (const float*)d_in[15];
  const float* w_g2   = (const float*)d_in[16];
  const float* b_g2   = (const float*)d_in[17];
  const float* w_b2   = (const float*)d_in[18];
  const float* b_b2   = (const float*)d_in[19];
  const float* w_sc   = (const float*)d_in[20];
  const float* b_sc   = (const float*)d_in[21];
  float* out = (float*)d_out;
  float* ws = (float*)d_ws;

  const size_t MF = 16777216;  // floats per 64MB region
  float* A  = ws;
  float* Br = ws + MF;
  float* Cr = ws + 2 * MF;
  float* SM = ws + 3 * MF;
  float* wdn   = SM;                     // 131072
  float* attnb = SM + 131072;            // up to 2097152
  float* mean1 = attnb + 2097152;
  float* rstd1 = mean1 + 512;
  float* mean2 = rstd1 + 512;
  float* rstd2 = mean2 + 256;
  float* gvec1 = rstd2 + 256;            // 8192
  float* bvec1 = gvec1 + 8192;
  float* gvec2 = bvec1 + 8192;           // 4096
  float* bvec2 = gvec2 + 4096;
  float* wsp   = bvec2 + 4096;
  u16* Wp1 = (u16*)wsp;                  // 9*256*512 ushorts
  u16* Wp2 = (u16*)(wsp + 655360);       // 9*256*256 ushorts

  float* img1   = A;                     // 4M floats
  float* ctx1   = A + 4194304;           // 4M
  u16*   Xt1    = (u16*)(A + 8388608);   // NHWC bf16
  float* gamma1 = Br;                    // 8M
  float* beta1  = Br + 8388608;          // 8M
  float* conv1o = Cr;                    // 16M
  float* img2   = A;                     // reuse
  float* ctx2   = Br;                    // reuse
  float* gamma2 = A;                     // reuse
  float* beta2  = out;                   // d_out as scratch until final conv
  u16*   Xt2    = (u16*)Br;              // reuse (ctx2 dead)
  float* scs    = Cr;                    // reuse (conv1o dead after act2)

  // ---- stage 1 ----
  bn_stats_kernel<<<dim3(CIN1), dim3(256), 0, stream>>>(x, mean1, rstd1, CIN1, P1);
  wdn_kernel<<<dim3(NB * LL), dim3(64), 0, stream>>>(wemb, wdn);
  pack_w_kernel<<<dim3(COUT * CIN1 / 256), dim3(256), 0, stream>>>(w_c1, Wp1, COUT, CIN1);
  pack_w_kernel<<<dim3(COUT * COUT / 256), dim3(256), 0, stream>>>(w_c2, Wp2, COUT, COUT);
  gemm_mfma_kernel<<<dim3(P1 / 128, TD / 128, NB), dim3(256), 0, stream>>>(
      w_img1, CIN1, 0, x, nullptr, img1, TD, CIN1, P1);
  attn_kernel<<<dim3(P1 / 4, NB), dim3(256), 0, stream>>>(img1, wdn, mask, attnb, P1);
  ctx_kernel<<<dim3(P1 / 64, NB), dim3(256), 0, stream>>>(attnb, wdn, ctx1, P1);
  gvec_kernel<<<dim3(CIN1 / 64, NB), dim3(64), 0, stream>>>(w_g1, b_g1, gcond, gvec1, CIN1);
  gvec_kernel<<<dim3(CIN1 / 64, NB), dim3(64), 0, stream>>>(w_b1, b_b1, gcond, bvec1, CIN1);
  gemm_mfma_kernel<<<dim3(P1 / 128, CIN1 / 128, NB), dim3(256), 0, stream>>>(
      w_g1, CONDC, GD, ctx1, gvec1, gamma1, CIN1, TD, P1);
  gemm_mfma_kernel<<<dim3(P1 / 128, CIN1 / 128, NB), dim3(256), 0, stream>>>(
      w_b1, CONDC, GD, ctx1, bvec1, beta1, CIN1, TD, P1);
  act_nhwc_kernel<<<dim3(P1 / 64, CIN1 / 32, NB), dim3(256), 0, stream>>>(
      x, gamma1, beta1, mean1, rstd1, bn1_w, bn1_b, Xt1, CIN1, P1);
  conv_mfma_kernel<CIN1, true><<<dim3(32, 2, NB), dim3(256), 0, stream>>>(
      Wp1, Xt1, nullptr, nullptr, conv1o);

  // ---- stage 2 ----
  bn_stats_kernel<<<dim3(COUT), dim3(256), 0, stream>>>(conv1o, mean2, rstd2, COUT, P2);
  gemm_mfma_kernel<<<dim3(P2 / 128, TD / 128, NB), dim3(256), 0, stream>>>(
      w_img2, COUT, 0, conv1o, nullptr, img2, TD, COUT, P2);
  attn_kernel<<<dim3(P2 / 4, NB), dim3(256), 0, stream>>>(img2, wdn, mask, attnb, P2);
  ctx_kernel<<<dim3(P2 / 64, NB), dim3(256), 0, stream>>>(attnb, wdn, ctx2, P2);
  gvec_kernel<<<dim3(COUT / 64, NB), dim3(64), 0, stream>>>(w_g2, b_g2, gcond, gvec2, COUT);
  gvec_kernel<<<dim3(COUT / 64, NB), dim3(64), 0, stream>>>(w_b2, b_b2, gcond, bvec2, COUT);
  gemm_mfma_kernel<<<dim3(P2 / 128, COUT / 128, NB), dim3(256), 0, stream>>>(
      w_g2, CONDC, GD, ctx2, gvec2, gamma2, COUT, TD, P2);
  gemm_mfma_kernel<<<dim3(P2 / 128, COUT / 128, NB), dim3(256), 0, stream>>>(
      w_b2, CONDC, GD, ctx2, bvec2, beta2, COUT, TD, P2);
  act_nhwc_kernel<<<dim3(P2 / 64, COUT / 32, NB), dim3(256), 0, stream>>>(
      conv1o, gamma2, beta2, mean2, rstd2, bn2_w, bn2_b, Xt2, COUT, P2);
  gemm_mfma_kernel<<<dim3(P1 / 128, COUT / 128, NB), dim3(256), 0, stream>>>(
      w_sc, CIN1, 0, x, nullptr, scs, COUT, CIN1, P1);
  conv_mfma_kernel<COUT, false><<<dim3(32, 2, NB), dim3(256), 0, stream>>>(
      Wp2, Xt2, scs, b_sc, out);
}

// Round 9
// 905.825 us; speedup vs baseline: 4.7595x; 1.0704x over previous
//
#include <hip/hip_runtime.h>
#include <hip/hip_bf16.h>
#include <math.h>

#define NB 16
#define CIN1 512
#define COUT 256
#define GD 256
#define TD 256
#define LL 32
#define P1 1024
#define P2 4096
#define CONDC 512

typedef __attribute__((ext_vector_type(8))) short bf16x8;
typedef __attribute__((ext_vector_type(4))) float f32x4;
typedef unsigned short u16;

__device__ __forceinline__ u16 f2b(float f) {
  __hip_bfloat16 h = __float2bfloat16(f);
  return *(u16*)&h;
}

// ---------------- BN stats: mean + rsqrt(var+eps) per channel ----------------
__global__ void bn_stats_kernel(const float* __restrict__ x, float* __restrict__ mean,
                                float* __restrict__ rstd, int C, int HW) {
  int c = blockIdx.x, t = threadIdx.x;
  float s = 0.f, sq = 0.f;
  for (int b = 0; b < NB; ++b) {
    const float* p = x + ((size_t)b * C + c) * HW;
    for (int i = t; i < HW; i += 256) { float v = p[i]; s += v; sq += v * v; }
  }
  __shared__ float ss[256], sq2[256];
  ss[t] = s; sq2[t] = sq; __syncthreads();
  for (int o = 128; o > 0; o >>= 1) {
    if (t < o) { ss[t] += ss[t + o]; sq2[t] += sq2[t + o]; }
    __syncthreads();
  }
  if (t == 0) {
    float n = (float)NB * (float)HW;
    float m = ss[0] / n;
    float v = sq2[0] / n - m * m;
    mean[c] = m;
    rstd[c] = rsqrtf(v + 1e-5f);
  }
}

// ---------------- normalize words_embs over channel dim per (b,l) ----------------
__global__ void wdn_kernel(const float* __restrict__ we, float* __restrict__ wdn) {
  int b = blockIdx.x >> 5, l = blockIdx.x & 31;
  int t = threadIdx.x; // 64
  const float* base = we + (size_t)b * TD * LL + l;
  float v[4]; float sq = 0.f;
#pragma unroll
  for (int k = 0; k < 4; ++k) { v[k] = base[(size_t)(t * 4 + k) * LL]; sq += v[k] * v[k]; }
#pragma unroll
  for (int o = 32; o > 0; o >>= 1) sq += __shfl_xor(sq, o);
  float r = 1.f / fmaxf(sqrtf(sq), 1e-12f);
  float* ob = wdn + (size_t)b * TD * LL + l;
#pragma unroll
  for (int k = 0; k < 4; ++k) ob[(size_t)(t * 4 + k) * LL] = v[k] * r;
}

// ---------------- per-pixel: l2norm(img col) -> sim vs wdn -> mask -> softmax ----------------
__global__ __launch_bounds__(256) void attn_kernel(const float* __restrict__ img,
                                                   const float* __restrict__ wdn,
                                                   const int* __restrict__ mask,
                                                   float* __restrict__ attn, int P) {
  __shared__ float imgs[4][TD];
  int wv = threadIdx.x >> 6, lane = threadIdx.x & 63;
  int p = blockIdx.x * 4 + wv, b = blockIdx.y;
  const float* ib = img + (size_t)b * TD * P + p;
  float v[4]; float sq = 0.f;
#pragma unroll
  for (int k = 0; k < 4; ++k) { v[k] = ib[(size_t)(lane * 4 + k) * P]; sq += v[k] * v[k]; }
#pragma unroll
  for (int o = 32; o > 0; o >>= 1) sq += __shfl_xor(sq, o);
  float rn = 1.f / fmaxf(sqrtf(sq), 1e-12f);
  *(float4*)&imgs[wv][lane * 4] = make_float4(v[0], v[1], v[2], v[3]);
  __syncthreads();
  int l = lane & 31, half = lane >> 5;
  const float* wb = wdn + (size_t)b * TD * LL + l;
  float sim = 0.f;
  int c0 = half * 128;
#pragma unroll 8
  for (int c = 0; c < 128; ++c) sim += imgs[wv][c0 + c] * wb[(size_t)(c0 + c) * LL];
  sim += __shfl_xor(sim, 32);
  sim *= rn;
  if (mask[b * LL + l] != 0) sim = -INFINITY;
  float m = sim;
#pragma unroll
  for (int o = 16; o > 0; o >>= 1) m = fmaxf(m, __shfl_xor(m, o));
  float e = expf(sim - m);
  float s = e;
#pragma unroll
  for (int o = 16; o > 0; o >>= 1) s += __shfl_xor(s, o);
  float a = e / s;
  if (half == 0) attn[((size_t)b * P + p) * LL + l] = a;
}

// ---------------- ctx[b,c,p] = sum_l attn[b,p,l]*wdn[b,c,l] ----------------
__global__ __launch_bounds__(256) void ctx_kernel(const float* __restrict__ attn,
                                                  const float* __restrict__ wdn,
                                                  float* __restrict__ ctx, int P) {
  __shared__ float wdns[TD * LL];   // 32 KB
  __shared__ float attns[64 * LL];  // 8 KB
  int b = blockIdx.y, p0 = blockIdx.x * 64, t = threadIdx.x;
  const float4* wsrc = (const float4*)(wdn + (size_t)b * TD * LL);
  for (int i = t; i < TD * LL / 4; i += 256) ((float4*)wdns)[i] = wsrc[i];
  const float4* asrc = (const float4*)(attn + ((size_t)b * P + p0) * LL);
  for (int i = t; i < 64 * LL / 4; i += 256) ((float4*)attns)[i] = asrc[i];
  __syncthreads();
  int pi = t & 63, cg = t >> 6;
  float a[LL];
#pragma unroll
  for (int l = 0; l < LL; l += 4) {
    float4 q = *(float4*)&attns[pi * LL + l];
    a[l] = q.x; a[l + 1] = q.y; a[l + 2] = q.z; a[l + 3] = q.w;
  }
  for (int k = 0; k < 64; ++k) {
    int c = cg * 64 + k;
    float acc = 0.f;
#pragma unroll
    for (int l = 0; l < LL; l += 4) {
      float4 w4 = *(float4*)&wdns[c * LL + l];
      acc += a[l] * w4.x + a[l + 1] * w4.y + a[l + 2] * w4.z + a[l + 3] * w4.w;
    }
    ctx[((size_t)b * TD + c) * P + p0 + pi] = acc;
  }
}

// ---------------- gvec[b,o] = bias[o] + sum_{c<GD} W[o,c]*gc[b,c] ----------------
__global__ void gvec_kernel(const float* __restrict__ Wg, const float* __restrict__ bias,
                            const float* __restrict__ gc, float* __restrict__ outv, int O) {
  int o = blockIdx.x * 64 + threadIdx.x;
  int b = blockIdx.y;
  if (o >= O) return;
  const float* wr = Wg + (size_t)o * CONDC;
  const float* g = gc + (size_t)b * GD;
  float s = 0.f;
  for (int c = 0; c < GD; ++c) s += wr[c] * g[c];
  outv[(size_t)b * O + o] = s + bias[o];
}

// ---------------- bf16 MFMA GEMM: Y[b,t,p] = vec[b,t] + sum_c W[t,c_off+c]*X[b,c,p] ----------------
// Block: 4 waves = 128 t x 128 p. Wave: 4x4 frags of 16x16x32. fp32->bf16 fused in staging.
// Xl uses XOR swizzle on c-blocks (block' = block ^ ((px>>4)&3)) to kill 16-way write conflicts.
// Wl row stride 44 u16 (conflict-free reads, 2-way writes).
__global__ __launch_bounds__(256) void gemm_mfma_kernel(
    const float* __restrict__ W, int ldw, int c_off,
    const float* __restrict__ X, const float* __restrict__ vec,
    float* __restrict__ Y, int T, int C, int P) {
  __shared__ u16 Wl[128 * 44];
  __shared__ u16 Xl[128 * 40];
  const int b = blockIdx.z;
  const int t0 = blockIdx.y * 128, p0 = blockIdx.x * 128;
  const int tid = threadIdx.x;
  const int w = tid >> 6, lane = tid & 63;
  const int wo = w >> 1, wq = w & 1;
  const int l15 = lane & 15, lg = lane >> 4;
  const float* Xb = X + (size_t)b * C * P;
  const int wr = tid >> 1, wcH = tid & 1;   // W staging: row, 16-float half
  const int xr = tid >> 3, xcG = tid & 7;   // X staging: c-row, 16-float px group
  const int csw = xr ^ ((xcG & 3) << 3);    // swizzled c position for X writes
  f32x4 acc[4][4] = {};

  for (int c0 = 0; c0 < C; c0 += 32) {
    // stage W tile (128 t x 32 c) -> Wl[t][c], stride 44
    {
      const float* src = W + (size_t)(t0 + wr) * ldw + c_off + c0 + wcH * 16;
      u16* dst = Wl + wr * 44 + wcH * 16;
#pragma unroll
      for (int j = 0; j < 4; ++j) {
        float4 v = *(const float4*)(src + j * 4);
        ushort4 pk = make_ushort4(f2b(v.x), f2b(v.y), f2b(v.z), f2b(v.w));
        *(ushort4*)(dst + j * 4) = pk;
      }
    }
    // stage X tile (32 c x 128 p) transposed -> Xl[p][c-swizzled], stride 40
    {
      const float* src = Xb + (size_t)(c0 + xr) * P + p0 + xcG * 16;
#pragma unroll
      for (int j = 0; j < 4; ++j) {
        float4 v = *(const float4*)(src + j * 4);
        int px = xcG * 16 + j * 4;
        Xl[(px + 0) * 40 + csw] = f2b(v.x);
        Xl[(px + 1) * 40 + csw] = f2b(v.y);
        Xl[(px + 2) * 40 + csw] = f2b(v.z);
        Xl[(px + 3) * 40 + csw] = f2b(v.w);
      }
    }
    __syncthreads();
    bf16x8 a[4], bb[4];
#pragma unroll
    for (int rr = 0; rr < 4; ++rr)
      a[rr] = *(const bf16x8*)(Wl + (wo * 64 + rr * 16 + l15) * 44 + lg * 8);
#pragma unroll
    for (int ss = 0; ss < 4; ++ss)
      bb[ss] = *(const bf16x8*)(Xl + (wq * 64 + ss * 16 + l15) * 40 + ((lg ^ ss) << 3));
#pragma unroll
    for (int rr = 0; rr < 4; ++rr)
#pragma unroll
      for (int ss = 0; ss < 4; ++ss)
        acc[rr][ss] = __builtin_amdgcn_mfma_f32_16x16x32_bf16(a[rr], bb[ss], acc[rr][ss], 0, 0, 0);
    __syncthreads();
  }
  // epilogue: C/D frag: col(p)=lane&15, row(t)=lg*4+k
#pragma unroll
  for (int rr = 0; rr < 4; ++rr) {
    int tb = t0 + wo * 64 + rr * 16 + lg * 4;
#pragma unroll
    for (int ss = 0; ss < 4; ++ss) {
      int p = p0 + wq * 64 + ss * 16 + l15;
#pragma unroll
      for (int k = 0; k < 4; ++k) {
        int t = tb + k;
        float val = acc[rr][ss][k];
        if (vec) val += vec[(size_t)b * T + t];
        Y[((size_t)b * T + t) * P + p] = val;
      }
    }
  }
}

// ---------------- fused: relu(gamma*BN(x)+beta) -> NHWC bf16 (LDS transpose) ----------------
__global__ __launch_bounds__(256) void act_nhwc_kernel(
    const float* __restrict__ xin, const float* __restrict__ gamma,
    const float* __restrict__ beta, const float* __restrict__ mean,
    const float* __restrict__ rstd, const float* __restrict__ bnw,
    const float* __restrict__ bnb, u16* __restrict__ outb, int C, int P) {
  __shared__ u16 Ts[32][68];
  int b = blockIdx.z, c0 = blockIdx.y * 32, p0 = blockIdx.x * 64;
  int tid = threadIdx.x;
  { // phase 1: compute 32c x 64px tile, rows coalesced
    int cr = tid >> 3, pg = tid & 7;
    int c = c0 + cr;
    size_t base = ((size_t)b * C + c) * P + p0 + pg * 8;
    float m = mean[c], r = rstd[c] * bnw[c], bb = bnb[c];
    float4 x1 = *(const float4*)(xin + base), x2 = *(const float4*)(xin + base + 4);
    float4 g1 = *(const float4*)(gamma + base), g2 = *(const float4*)(gamma + base + 4);
    float4 t1 = *(const float4*)(beta + base), t2 = *(const float4*)(beta + base + 4);
    float xv[8] = {x1.x, x1.y, x1.z, x1.w, x2.x, x2.y, x2.z, x2.w};
    float gv[8] = {g1.x, g1.y, g1.z, g1.w, g2.x, g2.y, g2.z, g2.w};
    float bv[8] = {t1.x, t1.y, t1.z, t1.w, t2.x, t2.y, t2.z, t2.w};
#pragma unroll
    for (int j = 0; j < 8; ++j) {
      float o = fmaxf(gv[j] * ((xv[j] - m) * r + bb) + bv[j], 0.f);
      Ts[cr][pg * 8 + j] = f2b(o);
    }
  }
  __syncthreads();
  { // phase 2: write NHWC, c contiguous
    int pr = tid >> 2, cg = tid & 3;
    union { u16 u[8]; uint4 v; } pk;
#pragma unroll
    for (int j = 0; j < 8; ++j) pk.u[j] = Ts[cg * 8 + j][pr];
    *(uint4*)(outb + ((size_t)b * P + p0 + pr) * C + c0 + cg * 8) = pk.v;
  }
}

// ---------------- pack conv weights: w[o][c][3][3] fp32 -> fragment-linear bf16 ----------------
// Wf[pos][c0blk][ot][lane=lg*16+l15][8c]  (wave A-load = 1KB contiguous)
__global__ void pack_w_kernel(const float* __restrict__ w, u16* __restrict__ wp, int O, int CIN) {
  int lin = blockIdx.x * 256 + threadIdx.x;
  if (lin >= O * CIN) return;
  int o = lin / CIN, c = lin - o * CIN;
  int c0blk = c >> 5, lg = (c >> 3) & 3, cc = c & 7;
  int ot = o >> 4, l15 = o & 15;
  int lane = lg * 16 + l15;
  size_t base = (((size_t)c0blk * (O >> 4) + ot) * 64 + lane) * 8 + cc;
  size_t posStride = (size_t)(CIN >> 5) * (O >> 4) * 512;
  const float* src = w + (size_t)lin * 9;
#pragma unroll
  for (int pos = 0; pos < 9; ++pos)
    wp[pos * posStride + base] = f2b(src[pos]);
}

// ---------------- bf16 MFMA implicit-GEMM 3x3 conv ----------------
// Double-buffered LDS + early-issue X staging + A-fragment software pipeline across pos.
template <int CIN, bool UP>
__global__ __launch_bounds__(256, 3) void conv_mfma_kernel(
    const u16* __restrict__ Wp, const u16* __restrict__ Xt,
    const float* __restrict__ scs, const float* __restrict__ scb,
    float* __restrict__ Y) {
  constexpr int S = UP ? 32 : 64;
  constexpr int NC0 = CIN >> 5;
  __shared__ u16 Xs[2][4 * 66 * 36];  // double buffer, 19008 B each
  const int b = blockIdx.z, oT = blockIdx.y, pxT = blockIdx.x;
  const int tid = threadIdx.x;
  const int w = tid >> 6, lane = tid & 63;
  const int wo = w >> 1, wp_ = w & 1;
  const int l15 = lane & 15, lg = lane >> 4;
  const int Y0 = pxT * 2;
  const u16* Xb = Xt + (size_t)b * S * S * CIN;
  const size_t posStride = (size_t)NC0 * 16 * 512;
  f32x4 acc[4][4] = {};
  uint2 st[9];

  // prologue: load + write tile 0
#pragma unroll
  for (int j = 0; j < 9; ++j) {
    int i = tid + j * 256;
    if (i < 2112) {
      int r = i / 528, rem = i - r * 528, col = rem >> 3, ch = rem & 7;
      int uy = Y0 - 1 + r, ux = col - 1;
      uint2 v = make_uint2(0u, 0u);
      if (uy >= 0 && uy < 64 && ux >= 0 && ux < 64) {
        int sy = UP ? (uy >> 1) : uy, sx = UP ? (ux >> 1) : ux;
        v = *(const uint2*)(Xb + ((size_t)sy * S + sx) * CIN + ch * 4);
      }
      st[j] = v;
    }
  }
#pragma unroll
  for (int j = 0; j < 9; ++j) {
    int i = tid + j * 256;
    if (i < 2112) {
      int r = i / 528, rem = i - r * 528, col = rem >> 3, ch = rem & 7;
      *(uint2*)(&Xs[0][(r * 66 + col) * 36 + ch * 4]) = st[j];
    }
  }
  __syncthreads();

  for (int c0b = 0; c0b < NC0; ++c0b) {
    const int cur = c0b & 1;
    // early-issue loads for next tile (land during compute)
    if (c0b + 1 < NC0) {
      const int c0n = (c0b + 1) << 5;
#pragma unroll
      for (int j = 0; j < 9; ++j) {
        int i = tid + j * 256;
        if (i < 2112) {
          int r = i / 528, rem = i - r * 528, col = rem >> 3, ch = rem & 7;
          int uy = Y0 - 1 + r, ux = col - 1;
          uint2 v = make_uint2(0u, 0u);
          if (uy >= 0 && uy < 64 && ux >= 0 && ux < 64) {
            int sy = UP ? (uy >> 1) : uy, sx = UP ? (ux >> 1) : ux;
            v = *(const uint2*)(Xb + ((size_t)sy * S + sx) * CIN + c0n + ch * 4);
          }
          st[j] = v;
        }
      }
    }
    // compute on current buffer, A-fragments software-pipelined across pos
    {
      const u16* wbB = Wp + ((size_t)c0b * 16 + oT * 8 + wo * 4) * 512 + lane * 8;
      bf16x8 aC[4], aN[4];
#pragma unroll
      for (int rr = 0; rr < 4; ++rr)
        aC[rr] = *(const bf16x8*)(wbB + rr * 512);
#pragma unroll
      for (int pos = 0; pos < 9; ++pos) {
        const int ky = pos / 3, kx = pos - ky * 3;
        if (pos < 8) {
          const u16* wbn = wbB + (size_t)(pos + 1) * posStride;
#pragma unroll
          for (int rr = 0; rr < 4; ++rr)
            aN[rr] = *(const bf16x8*)(wbn + rr * 512);
        }
        const int rowb = ((wp_ + ky) * 66 + kx) * 36 + lg * 8;
#pragma unroll
        for (int ss = 0; ss < 4; ++ss) {
          int idx = rowb + (ss * 16 + l15) * 36;
          union { uint2 q[2]; bf16x8 v; } u;
          u.q[0] = *(const uint2*)(&Xs[cur][idx]);
          u.q[1] = *(const uint2*)(&Xs[cur][idx + 4]);
#pragma unroll
          for (int rr = 0; rr < 4; ++rr)
            acc[rr][ss] = __builtin_amdgcn_mfma_f32_16x16x32_bf16(aC[rr], u.v, acc[rr][ss], 0, 0, 0);
        }
#pragma unroll
        for (int rr = 0; rr < 4; ++rr) aC[rr] = aN[rr];
      }
    }
    // write next tile into the other buffer; single barrier per iter
    if (c0b + 1 < NC0) {
#pragma unroll
      for (int j = 0; j < 9; ++j) {
        int i = tid + j * 256;
        if (i < 2112) {
          int r = i / 528, rem = i - r * 528, col = rem >> 3, ch = rem & 7;
          *(uint2*)(&Xs[cur ^ 1][(r * 66 + col) * 36 + ch * 4]) = st[j];
        }
      }
      __syncthreads();
    }
  }
  const int oBase = oT * 128 + wo * 64 + lg * 4;
  const int pxBase = pxT * 128 + wp_ * 64 + l15;
#pragma unroll
  for (int rr = 0; rr < 4; ++rr) {
#pragma unroll
    for (int ss = 0; ss < 4; ++ss) {
      int px = pxBase + ss * 16;
#pragma unroll
      for (int k = 0; k < 4; ++k) {
        int o = oBase + rr * 16 + k;
        float val = acc[rr][ss][k];
        if (scs) {
          int gx = px & 63;
          val += scs[((size_t)b * COUT + o) * P1 + pxT * 32 + (gx >> 1)] + scb[o];
        }
        Y[((size_t)b * COUT + o) * 4096 + px] = val;
      }
    }
  }
}

extern "C" void kernel_launch(void* const* d_in, const int* in_sizes, int n_in,
                              void* d_out, int out_size, void* d_ws, size_t ws_size,
                              hipStream_t stream) {
  const float* x      = (const float*)d_in[0];
  const float* gcond  = (const float*)d_in[1];
  const float* wemb   = (const float*)d_in[2];
  const int*   mask   = (const int*)d_in[3];
  const float* w_img1 = (const float*)d_in[4];
  const float* w_img2 = (const float*)d_in[5];
  const float* w_c1   = (const float*)d_in[6];
  const float* w_c2   = (const float*)d_in[7];
  const float* bn1_w  = (const float*)d_in[8];
  const float* bn1_b  = (const float*)d_in[9];
  const float* bn2_w  = (const float*)d_in[10];
  const float* bn2_b  = (const float*)d_in[11];
  const float* w_g1   = (const float*)d_in[12];
  const float* b_g1   = (const float*)d_in[13];
  const float* w_b1   = (const float*)d_in[14];
  const float* b_b1   = (const float*)d_in[15];
  const float* w_g2   = (const float*)d_in[16];
  const float* b_g2   = (const float*)d_in[17];
  const float* w_b2   = (const float*)d_in[18];
  const float* b_b2   = (const float*)d_in[19];
  const float* w_sc   = (const float*)d_in[20];
  const float* b_sc   = (const float*)d_in[21];
  float* out = (float*)d_out;
  float* ws = (float*)d_ws;

  const size_t MF = 16777216;  // floats per 64MB region
  float* A  = ws;
  float* Br = ws + MF;
  float* Cr = ws + 2 * MF;
  float* SM = ws + 3 * MF;
  float* wdn   = SM;                     // 131072
  float* attnb = SM + 131072;            // up to 2097152
  float* mean1 = attnb + 2097152;
  float* rstd1 = mean1 + 512;
  float* mean2 = rstd1 + 512;
  float* rstd2 = mean2 + 256;
  float* gvec1 = rstd2 + 256;            // 8192
  float* bvec1 = gvec1 + 8192;
  float* gvec2 = bvec1 + 8192;           // 4096
  float* bvec2 = gvec2 + 4096;
  float* wsp   = bvec2 + 4096;
  u16* Wp1 = (u16*)wsp;                  // 9*256*512 ushorts
  u16* Wp2 = (u16*)(wsp + 655360);       // 9*256*256 ushorts

  float* img1   = A;                     // 4M floats
  float* ctx1   = A + 4194304;           // 4M
  u16*   Xt1    = (u16*)(A + 8388608);   // NHWC bf16
  float* gamma1 = Br;                    // 8M
  float* beta1  = Br + 8388608;          // 8M
  float* conv1o = Cr;                    // 16M
  float* img2   = A;                     // reuse
  float* ctx2   = Br;                    // reuse
  float* gamma2 = A;                     // reuse
  float* beta2  = out;                   // d_out as scratch until final conv
  u16*   Xt2    = (u16*)Br;              // reuse (ctx2 dead)
  float* scs    = Cr;                    // reuse (conv1o dead after act2)

  // ---- stage 1 ----
  bn_stats_kernel<<<dim3(CIN1), dim3(256), 0, stream>>>(x, mean1, rstd1, CIN1, P1);
  wdn_kernel<<<dim3(NB * LL), dim3(64), 0, stream>>>(wemb, wdn);
  pack_w_kernel<<<dim3(COUT * CIN1 / 256), dim3(256), 0, stream>>>(w_c1, Wp1, COUT, CIN1);
  pack_w_kernel<<<dim3(COUT * COUT / 256), dim3(256), 0, stream>>>(w_c2, Wp2, COUT, COUT);
  gemm_mfma_kernel<<<dim3(P1 / 128, TD / 128, NB), dim3(256), 0, stream>>>(
      w_img1, CIN1, 0, x, nullptr, img1, TD, CIN1, P1);
  attn_kernel<<<dim3(P1 / 4, NB), dim3(256), 0, stream>>>(img1, wdn, mask, attnb, P1);
  ctx_kernel<<<dim3(P1 / 64, NB), dim3(256), 0, stream>>>(attnb, wdn, ctx1, P1);
  gvec_kernel<<<dim3(CIN1 / 64, NB), dim3(64), 0, stream>>>(w_g1, b_g1, gcond, gvec1, CIN1);
  gvec_kernel<<<dim3(CIN1 / 64, NB), dim3(64), 0, stream>>>(w_b1, b_b1, gcond, bvec1, CIN1);
  gemm_mfma_kernel<<<dim3(P1 / 128, CIN1 / 128, NB), dim3(256), 0, stream>>>(
      w_g1, CONDC, GD, ctx1, gvec1, gamma1, CIN1, TD, P1);
  gemm_mfma_kernel<<<dim3(P1 / 128, CIN1 / 128, NB), dim3(256), 0, stream>>>(
      w_b1, CONDC, GD, ctx1, bvec1, beta1, CIN1, TD, P1);
  act_nhwc_kernel<<<dim3(P1 / 64, CIN1 / 32, NB), dim3(256), 0, stream>>>(
      x, gamma1, beta1, mean1, rstd1, bn1_w, bn1_b, Xt1, CIN1, P1);
  conv_mfma_kernel<CIN1, true><<<dim3(32, 2, NB), dim3(256), 0, stream>>>(
      Wp1, Xt1, nullptr, nullptr, conv1o);

  // ---- stage 2 ----
  bn_stats_kernel<<<dim3(COUT), dim3(256), 0, stream>>>(conv1o, mean2, rstd2, COUT, P2);
  gemm_mfma_kernel<<<dim3(P2 / 128, TD / 128, NB), dim3(256), 0, stream>>>(
      w_img2, COUT, 0, conv1o, nullptr, img2, TD, COUT, P2);
  attn_kernel<<<dim3(P2 / 4, NB), dim3(256), 0, stream>>>(img2, wdn, mask, attnb, P2);
  ctx_kernel<<<dim3(P2 / 64, NB), dim3(256), 0, stream>>>(attnb, wdn, ctx2, P2);
  gvec_kernel<<<dim3(COUT / 64, NB), dim3(64), 0, stream>>>(w_g2, b_g2, gcond, gvec2, COUT);
  gvec_kernel<<<dim3(COUT / 64, NB), dim3(64), 0, stream>>>(w_b2, b_b2, gcond, bvec2, COUT);
  gemm_mfma_kernel<<<dim3(P2 / 128, COUT / 128, NB), dim3(256), 0, stream>>>(
      w_g2, CONDC, GD, ctx2, gvec2, gamma2, COUT, TD, P2);
  gemm_mfma_kernel<<<dim3(P2 / 128, COUT / 128, NB), dim3(256), 0, stream>>>(
      w_b2, CONDC, GD, ctx2, bvec2, beta2, COUT, TD, P2);
  act_nhwc_kernel<<<dim3(P2 / 64, COUT / 32, NB), dim3(256), 0, stream>>>(
      conv1o, gamma2, beta2, mean2, rstd2, bn2_w, bn2_b, Xt2, COUT, P2);
  gemm_mfma_kernel<<<dim3(P1 / 128, COUT / 128, NB), dim3(256), 0, stream>>>(
      w_sc, CIN1, 0, x, nullptr, scs, COUT, CIN1, P1);
  conv_mfma_kernel<COUT, false><<<dim3(32, 2, NB), dim3(256), 0, stream>>>(
      Wp2, Xt2, scs, b_sc, out);
}

// Round 10
// 676.500 us; speedup vs baseline: 6.3729x; 1.3390x over previous
//
#include <hip/hip_runtime.h>
#include <hip/hip_bf16.h>
#include <math.h>

#define NB 16
#define CIN1 512
#define COUT 256
#define GD 256
#define TD 256
#define LL 32
#define P1 1024
#define P2 4096
#define CONDC 512

typedef __attribute__((ext_vector_type(8))) short bf16x8;
typedef __attribute__((ext_vector_type(4))) float f32x4;
typedef unsigned short u16;

__device__ __forceinline__ u16 f2b(float f) {
  __hip_bfloat16 h = __float2bfloat16(f);
  return *(u16*)&h;
}

// ---------------- BN stats: mean + rsqrt(var+eps) per channel ----------------
__global__ void bn_stats_kernel(const float* __restrict__ x, float* __restrict__ mean,
                                float* __restrict__ rstd, int C, int HW) {
  int c = blockIdx.x, t = threadIdx.x;
  float s = 0.f, sq = 0.f;
  for (int b = 0; b < NB; ++b) {
    const float* p = x + ((size_t)b * C + c) * HW;
    for (int i = t; i < HW; i += 256) { float v = p[i]; s += v; sq += v * v; }
  }
  __shared__ float ss[256], sq2[256];
  ss[t] = s; sq2[t] = sq; __syncthreads();
  for (int o = 128; o > 0; o >>= 1) {
    if (t < o) { ss[t] += ss[t + o]; sq2[t] += sq2[t + o]; }
    __syncthreads();
  }
  if (t == 0) {
    float n = (float)NB * (float)HW;
    float m = ss[0] / n;
    float v = sq2[0] / n - m * m;
    mean[c] = m;
    rstd[c] = rsqrtf(v + 1e-5f);
  }
}

// ---------------- normalize words_embs over channel dim per (b,l) ----------------
__global__ void wdn_kernel(const float* __restrict__ we, float* __restrict__ wdn) {
  int b = blockIdx.x >> 5, l = blockIdx.x & 31;
  int t = threadIdx.x; // 64
  const float* base = we + (size_t)b * TD * LL + l;
  float v[4]; float sq = 0.f;
#pragma unroll
  for (int k = 0; k < 4; ++k) { v[k] = base[(size_t)(t * 4 + k) * LL]; sq += v[k] * v[k]; }
#pragma unroll
  for (int o = 32; o > 0; o >>= 1) sq += __shfl_xor(sq, o);
  float r = 1.f / fmaxf(sqrtf(sq), 1e-12f);
  float* ob = wdn + (size_t)b * TD * LL + l;
#pragma unroll
  for (int k = 0; k < 4; ++k) ob[(size_t)(t * 4 + k) * LL] = v[k] * r;
}

// ---------------- gvec[b,o] = bias[o] + sum_{c<GD} W[o,c]*gc[b,c] ----------------
__global__ void gvec_kernel(const float* __restrict__ Wg, const float* __restrict__ bias,
                            const float* __restrict__ gc, float* __restrict__ outv, int O) {
  int o = blockIdx.x * 64 + threadIdx.x;
  int b = blockIdx.y;
  if (o >= O) return;
  const float* wr = Wg + (size_t)o * CONDC;
  const float* g = gc + (size_t)b * GD;
  float s = 0.f;
  for (int c = 0; c < GD; ++c) s += wr[c] * g[c];
  outv[(size_t)b * O + o] = s + bias[o];
}

// ---------------- fused attention: l2norm -> sim (MFMA) -> softmax -> ctx (MFMA) ----------------
// Block: 64 pixels, 4 waves. sim = img^T(px,t) x wdn(t,l); ctx = wdnC(c,l) x attn(l,px).
__global__ __launch_bounds__(256) void attnctx_kernel(
    const float* __restrict__ img, const float* __restrict__ wdn,
    const int* __restrict__ mask, float* __restrict__ ctx, int P) {
  __shared__ u16 imgT[64 * 72];     // [px][64t chunk], stride 72 (16B aligned rows)
  __shared__ u16 wdnT[32 * 264];    // [l][256t]
  __shared__ u16 wdnC[256 * 40];    // [c][32l]
  __shared__ u16 attnB[64 * 40];    // [px][32l]
  __shared__ float sqP[4][64];
  __shared__ float rnL[64];
  const int b = blockIdx.y, p0 = blockIdx.x * 64;
  const int tid = threadIdx.x;
  const int w = tid >> 6, lane = tid & 63;
  const int l15 = lane & 15, lg = lane >> 4;
  const float* ib = img + (size_t)b * TD * P;
  const float* wb = wdn + (size_t)b * TD * LL;

  // stage wdn both layouts (bf16)
  for (int i = tid; i < TD * LL; i += 256) {
    int t = i >> 5, l = i & 31;
    u16 v = f2b(wb[i]);
    wdnT[l * 264 + t] = v;
    wdnC[t * 40 + l] = v;
  }

  f32x4 s0 = {}, s1 = {};
  float ssq = 0.f;
  for (int q = 0; q < 4; ++q) {
    // stage img chunk: wave w stages local t rows [w*16, w*16+16), col = p0+lane
#pragma unroll
    for (int i = 0; i < 16; i += 2) {
      int t = q * 64 + w * 16 + i;
      float v0 = ib[(size_t)t * P + p0 + lane];
      float v1 = ib[(size_t)(t + 1) * P + p0 + lane];
      ssq += v0 * v0 + v1 * v1;
      unsigned pk = (unsigned)f2b(v0) | ((unsigned)f2b(v1) << 16);
      *(unsigned*)(imgT + lane * 72 + w * 16 + i) = pk;
    }
    __syncthreads();
#pragma unroll
    for (int ks = 0; ks < 2; ++ks) {
      bf16x8 a = *(const bf16x8*)(imgT + (w * 16 + l15) * 72 + ks * 32 + lg * 8);
      bf16x8 b0 = *(const bf16x8*)(wdnT + l15 * 264 + q * 64 + ks * 32 + lg * 8);
      bf16x8 b1 = *(const bf16x8*)(wdnT + (16 + l15) * 264 + q * 64 + ks * 32 + lg * 8);
      s0 = __builtin_amdgcn_mfma_f32_16x16x32_bf16(a, b0, s0, 0, 0, 0);
      s1 = __builtin_amdgcn_mfma_f32_16x16x32_bf16(a, b1, s1, 0, 0, 0);
    }
    __syncthreads();
  }
  sqP[w][lane] = ssq;
  __syncthreads();
  if (tid < 64) {
    float s = sqP[0][tid] + sqP[1][tid] + sqP[2][tid] + sqP[3][tid];
    rnL[tid] = 1.f / fmaxf(sqrtf(s), 1e-12f);
  }
  __syncthreads();
  // softmax: lane holds rows px = w*16+lg*4+k, cols l = l15 (s0) and 16+l15 (s1)
  const bool m0 = mask[b * LL + l15] != 0;
  const bool m1 = mask[b * LL + 16 + l15] != 0;
#pragma unroll
  for (int k = 0; k < 4; ++k) {
    float rn = rnL[w * 16 + lg * 4 + k];
    float v0 = m0 ? -INFINITY : s0[k] * rn;
    float v1 = m1 ? -INFINITY : s1[k] * rn;
    float mx = fmaxf(v0, v1);
#pragma unroll
    for (int o = 1; o < 16; o <<= 1) mx = fmaxf(mx, __shfl_xor(mx, o));
    float e0 = expf(v0 - mx), e1 = expf(v1 - mx);
    float sm = e0 + e1;
#pragma unroll
    for (int o = 1; o < 16; o <<= 1) sm += __shfl_xor(sm, o);
    float inv = 1.f / sm;
    int px = w * 16 + lg * 4 + k;
    attnB[px * 40 + l15] = f2b(e0 * inv);
    attnB[px * 40 + 16 + l15] = f2b(e1 * inv);
  }
  __syncthreads();
  // ctx: A = wdnC[c][l] (wave c-tiles w*4..w*4+3), B = attnB[px][l], K = 32
  f32x4 acc[4][4] = {};
  bf16x8 bfr[4];
#pragma unroll
  for (int pt = 0; pt < 4; ++pt)
    bfr[pt] = *(const bf16x8*)(attnB + (pt * 16 + l15) * 40 + lg * 8);
#pragma unroll
  for (int cc = 0; cc < 4; ++cc) {
    bf16x8 a = *(const bf16x8*)(wdnC + ((w * 4 + cc) * 16 + l15) * 40 + lg * 8);
#pragma unroll
    for (int pt = 0; pt < 4; ++pt)
      acc[cc][pt] = __builtin_amdgcn_mfma_f32_16x16x32_bf16(a, bfr[pt], acc[cc][pt], 0, 0, 0);
  }
#pragma unroll
  for (int cc = 0; cc < 4; ++cc) {
#pragma unroll
    for (int pt = 0; pt < 4; ++pt) {
#pragma unroll
      for (int k = 0; k < 4; ++k) {
        int c = (w * 4 + cc) * 16 + lg * 4 + k;
        ctx[((size_t)b * TD + c) * P + p0 + pt * 16 + l15] = acc[cc][pt][k];
      }
    }
  }
}

// ---------------- bf16 MFMA GEMM (img1/img2/shortcut): Y = W x X ----------------
__global__ __launch_bounds__(256) void gemm_mfma_kernel(
    const float* __restrict__ W, int ldw, int c_off,
    const float* __restrict__ X, const float* __restrict__ vec,
    float* __restrict__ Y, int T, int C, int P) {
  __shared__ u16 Wl[128 * 44];
  __shared__ u16 Xl[128 * 40];
  const int b = blockIdx.z;
  const int t0 = blockIdx.y * 128, p0 = blockIdx.x * 128;
  const int tid = threadIdx.x;
  const int w = tid >> 6, lane = tid & 63;
  const int wo = w >> 1, wq = w & 1;
  const int l15 = lane & 15, lg = lane >> 4;
  const float* Xb = X + (size_t)b * C * P;
  const int wr = tid >> 1, wcH = tid & 1;
  const int xr = tid >> 3, xcG = tid & 7;
  const int csw = xr ^ ((xcG & 3) << 3);
  f32x4 acc[4][4] = {};

  for (int c0 = 0; c0 < C; c0 += 32) {
    {
      const float* src = W + (size_t)(t0 + wr) * ldw + c_off + c0 + wcH * 16;
      u16* dst = Wl + wr * 44 + wcH * 16;
#pragma unroll
      for (int j = 0; j < 4; ++j) {
        float4 v = *(const float4*)(src + j * 4);
        ushort4 pk = make_ushort4(f2b(v.x), f2b(v.y), f2b(v.z), f2b(v.w));
        *(ushort4*)(dst + j * 4) = pk;
      }
    }
    {
      const float* src = Xb + (size_t)(c0 + xr) * P + p0 + xcG * 16;
#pragma unroll
      for (int j = 0; j < 4; ++j) {
        float4 v = *(const float4*)(src + j * 4);
        int px = xcG * 16 + j * 4;
        Xl[(px + 0) * 40 + csw] = f2b(v.x);
        Xl[(px + 1) * 40 + csw] = f2b(v.y);
        Xl[(px + 2) * 40 + csw] = f2b(v.z);
        Xl[(px + 3) * 40 + csw] = f2b(v.w);
      }
    }
    __syncthreads();
    bf16x8 a[4], bb[4];
#pragma unroll
    for (int rr = 0; rr < 4; ++rr)
      a[rr] = *(const bf16x8*)(Wl + (wo * 64 + rr * 16 + l15) * 44 + lg * 8);
#pragma unroll
    for (int ss = 0; ss < 4; ++ss)
      bb[ss] = *(const bf16x8*)(Xl + (wq * 64 + ss * 16 + l15) * 40 + ((lg ^ ss) << 3));
#pragma unroll
    for (int rr = 0; rr < 4; ++rr)
#pragma unroll
      for (int ss = 0; ss < 4; ++ss)
        acc[rr][ss] = __builtin_amdgcn_mfma_f32_16x16x32_bf16(a[rr], bb[ss], acc[rr][ss], 0, 0, 0);
    __syncthreads();
  }
#pragma unroll
  for (int rr = 0; rr < 4; ++rr) {
    int tb = t0 + wo * 64 + rr * 16 + lg * 4;
#pragma unroll
    for (int ss = 0; ss < 4; ++ss) {
      int p = p0 + wq * 64 + ss * 16 + l15;
#pragma unroll
      for (int k = 0; k < 4; ++k) {
        int t = tb + k;
        float val = acc[rr][ss][k];
        if (vec) val += vec[(size_t)b * T + t];
        Y[((size_t)b * T + t) * P + p] = val;
      }
    }
  }
}

// ---------------- fused gamma/beta GEMM + BN + ReLU + NHWC bf16 pack ----------------
// Block 128c x 128p; dual accumulators (gamma, beta) share staged ctx tile.
__global__ __launch_bounds__(256, 1) void gbact_kernel(
    const float* __restrict__ Wg, const float* __restrict__ Wb,
    const float* __restrict__ ctx, const float* __restrict__ gvec,
    const float* __restrict__ bvec, const float* __restrict__ xin,
    const float* __restrict__ mean, const float* __restrict__ rstd,
    const float* __restrict__ bnw, const float* __restrict__ bnb,
    u16* __restrict__ outb, int C, int P) {
  __shared__ u16 shmem[17408];  // staging (16384) / transpose 128x136 (17408)
  u16* Wgl = shmem;             // 128*44
  u16* Wbl = shmem + 5632;      // 128*44
  u16* Xl  = shmem + 11264;     // 128*40
  const int b = blockIdx.z, t0 = blockIdx.y * 128, p0 = blockIdx.x * 128;
  const int tid = threadIdx.x;
  const int w = tid >> 6, lane = tid & 63;
  const int wo = w >> 1, wq = w & 1;
  const int l15 = lane & 15, lg = lane >> 4;
  const float* Xb = ctx + (size_t)b * TD * P;
  const int wr = tid >> 1, wcH = tid & 1;
  const int xr = tid >> 3, xcG = tid & 7;
  const int csw = xr ^ ((xcG & 3) << 3);
  f32x4 accg[4][4] = {}, accb[4][4] = {};

  for (int c0 = 0; c0 < TD; c0 += 32) {
    {
      const float* sg = Wg + (size_t)(t0 + wr) * CONDC + GD + c0 + wcH * 16;
      const float* sb = Wb + (size_t)(t0 + wr) * CONDC + GD + c0 + wcH * 16;
      u16* dg = Wgl + wr * 44 + wcH * 16;
      u16* db = Wbl + wr * 44 + wcH * 16;
#pragma unroll
      for (int j = 0; j < 4; ++j) {
        float4 v = *(const float4*)(sg + j * 4);
        *(ushort4*)(dg + j * 4) = make_ushort4(f2b(v.x), f2b(v.y), f2b(v.z), f2b(v.w));
        float4 u = *(const float4*)(sb + j * 4);
        *(ushort4*)(db + j * 4) = make_ushort4(f2b(u.x), f2b(u.y), f2b(u.z), f2b(u.w));
      }
    }
    {
      const float* src = Xb + (size_t)(c0 + xr) * P + p0 + xcG * 16;
#pragma unroll
      for (int j = 0; j < 4; ++j) {
        float4 v = *(const float4*)(src + j * 4);
        int px = xcG * 16 + j * 4;
        Xl[(px + 0) * 40 + csw] = f2b(v.x);
        Xl[(px + 1) * 40 + csw] = f2b(v.y);
        Xl[(px + 2) * 40 + csw] = f2b(v.z);
        Xl[(px + 3) * 40 + csw] = f2b(v.w);
      }
    }
    __syncthreads();
    bf16x8 ag[4], ab[4], bb[4];
#pragma unroll
    for (int rr = 0; rr < 4; ++rr) {
      ag[rr] = *(const bf16x8*)(Wgl + (wo * 64 + rr * 16 + l15) * 44 + lg * 8);
      ab[rr] = *(const bf16x8*)(Wbl + (wo * 64 + rr * 16 + l15) * 44 + lg * 8);
    }
#pragma unroll
    for (int ss = 0; ss < 4; ++ss)
      bb[ss] = *(const bf16x8*)(Xl + (wq * 64 + ss * 16 + l15) * 40 + ((lg ^ ss) << 3));
#pragma unroll
    for (int rr = 0; rr < 4; ++rr)
#pragma unroll
      for (int ss = 0; ss < 4; ++ss) {
        accg[rr][ss] = __builtin_amdgcn_mfma_f32_16x16x32_bf16(ag[rr], bb[ss], accg[rr][ss], 0, 0, 0);
        accb[rr][ss] = __builtin_amdgcn_mfma_f32_16x16x32_bf16(ab[rr], bb[ss], accb[rr][ss], 0, 0, 0);
      }
    __syncthreads();
  }
  // epilogue: gamma*BN(x)+beta, ReLU, bf16 -> LDS transpose [p][c] stride 136
#pragma unroll
  for (int rr = 0; rr < 4; ++rr) {
    float gv[4], bv[4], mm[4], rs[4], bB[4];
#pragma unroll
    for (int k = 0; k < 4; ++k) {
      int c = t0 + wo * 64 + rr * 16 + lg * 4 + k;
      gv[k] = gvec[(size_t)b * C + c];
      bv[k] = bvec[(size_t)b * C + c];
      mm[k] = mean[c]; rs[k] = rstd[c] * bnw[c]; bB[k] = bnb[c];
    }
#pragma unroll
    for (int ss = 0; ss < 4; ++ss) {
#pragma unroll
      for (int k = 0; k < 4; ++k) {
        int cl = wo * 64 + rr * 16 + lg * 4 + k;
        int pl = wq * 64 + ss * 16 + l15;
        float xv = xin[((size_t)b * C + t0 + cl) * P + p0 + pl];
        float g = accg[rr][ss][k] + gv[k];
        float be = accb[rr][ss][k] + bv[k];
        float val = fmaxf(g * ((xv - mm[k]) * rs[k] + bB[k]) + be, 0.f);
        shmem[pl * 136 + cl] = f2b(val);
      }
    }
  }
  __syncthreads();
  // coalesced NHWC store
  const int pr = tid >> 1, h = tid & 1;
#pragma unroll
  for (int j = 0; j < 8; ++j) {
    uint4 v = *(uint4*)(shmem + pr * 136 + h * 64 + j * 8);
    *(uint4*)(outb + ((size_t)b * P + p0 + pr) * C + t0 + h * 64 + j * 8) = v;
  }
}

// ---------------- pack conv weights: fragment-linear bf16 ----------------
__global__ void pack_w_kernel(const float* __restrict__ w, u16* __restrict__ wp, int O, int CIN) {
  int lin = blockIdx.x * 256 + threadIdx.x;
  if (lin >= O * CIN) return;
  int o = lin / CIN, c = lin - o * CIN;
  int c0blk = c >> 5, lg = (c >> 3) & 3, cc = c & 7;
  int ot = o >> 4, l15 = o & 15;
  int lane = lg * 16 + l15;
  size_t base = (((size_t)c0blk * (O >> 4) + ot) * 64 + lane) * 8 + cc;
  size_t posStride = (size_t)(CIN >> 5) * (O >> 4) * 512;
  const float* src = w + (size_t)lin * 9;
#pragma unroll
  for (int pos = 0; pos < 9; ++pos)
    wp[pos * posStride + base] = f2b(src[pos]);
}

// ---------------- bf16 MFMA implicit-GEMM 3x3 conv (dbuf + A pipeline) ----------------
template <int CIN, bool UP>
__global__ __launch_bounds__(256, 3) void conv_mfma_kernel(
    const u16* __restrict__ Wp, const u16* __restrict__ Xt,
    const float* __restrict__ scs, const float* __restrict__ scb,
    float* __restrict__ Y) {
  constexpr int S = UP ? 32 : 64;
  constexpr int NC0 = CIN >> 5;
  __shared__ u16 Xs[2][4 * 66 * 36];
  const int b = blockIdx.z, oT = blockIdx.y, pxT = blockIdx.x;
  const int tid = threadIdx.x;
  const int w = tid >> 6, lane = tid & 63;
  const int wo = w >> 1, wp_ = w & 1;
  const int l15 = lane & 15, lg = lane >> 4;
  const int Y0 = pxT * 2;
  const u16* Xb = Xt + (size_t)b * S * S * CIN;
  const size_t posStride = (size_t)NC0 * 16 * 512;
  f32x4 acc[4][4] = {};
  uint2 st[9];

#pragma unroll
  for (int j = 0; j < 9; ++j) {
    int i = tid + j * 256;
    if (i < 2112) {
      int r = i / 528, rem = i - r * 528, col = rem >> 3, ch = rem & 7;
      int uy = Y0 - 1 + r, ux = col - 1;
      uint2 v = make_uint2(0u, 0u);
      if (uy >= 0 && uy < 64 && ux >= 0 && ux < 64) {
        int sy = UP ? (uy >> 1) : uy, sx = UP ? (ux >> 1) : ux;
        v = *(const uint2*)(Xb + ((size_t)sy * S + sx) * CIN + ch * 4);
      }
      st[j] = v;
    }
  }
#pragma unroll
  for (int j = 0; j < 9; ++j) {
    int i = tid + j * 256;
    if (i < 2112) {
      int r = i / 528, rem = i - r * 528, col = rem >> 3, ch = rem & 7;
      *(uint2*)(&Xs[0][(r * 66 + col) * 36 + ch * 4]) = st[j];
    }
  }
  __syncthreads();

  for (int c0b = 0; c0b < NC0; ++c0b) {
    const int cur = c0b & 1;
    if (c0b + 1 < NC0) {
      const int c0n = (c0b + 1) << 5;
#pragma unroll
      for (int j = 0; j < 9; ++j) {
        int i = tid + j * 256;
        if (i < 2112) {
          int r = i / 528, rem = i - r * 528, col = rem >> 3, ch = rem & 7;
          int uy = Y0 - 1 + r, ux = col - 1;
          uint2 v = make_uint2(0u, 0u);
          if (uy >= 0 && uy < 64 && ux >= 0 && ux < 64) {
            int sy = UP ? (uy >> 1) : uy, sx = UP ? (ux >> 1) : ux;
            v = *(const uint2*)(Xb + ((size_t)sy * S + sx) * CIN + c0n + ch * 4);
          }
          st[j] = v;
        }
      }
    }
    {
      const u16* wbB = Wp + ((size_t)c0b * 16 + oT * 8 + wo * 4) * 512 + lane * 8;
      bf16x8 aC[4], aN[4];
#pragma unroll
      for (int rr = 0; rr < 4; ++rr)
        aC[rr] = *(const bf16x8*)(wbB + rr * 512);
#pragma unroll
      for (int pos = 0; pos < 9; ++pos) {
        const int ky = pos / 3, kx = pos - ky * 3;
        if (pos < 8) {
          const u16* wbn = wbB + (size_t)(pos + 1) * posStride;
#pragma unroll
          for (int rr = 0; rr < 4; ++rr)
            aN[rr] = *(const bf16x8*)(wbn + rr * 512);
        }
        const int rowb = ((wp_ + ky) * 66 + kx) * 36 + lg * 8;
#pragma unroll
        for (int ss = 0; ss < 4; ++ss) {
          int idx = rowb + (ss * 16 + l15) * 36;
          union { uint2 q[2]; bf16x8 v; } u;
          u.q[0] = *(const uint2*)(&Xs[cur][idx]);
          u.q[1] = *(const uint2*)(&Xs[cur][idx + 4]);
#pragma unroll
          for (int rr = 0; rr < 4; ++rr)
            acc[rr][ss] = __builtin_amdgcn_mfma_f32_16x16x32_bf16(aC[rr], u.v, acc[rr][ss], 0, 0, 0);
        }
#pragma unroll
        for (int rr = 0; rr < 4; ++rr) aC[rr] = aN[rr];
      }
    }
    if (c0b + 1 < NC0) {
#pragma unroll
      for (int j = 0; j < 9; ++j) {
        int i = tid + j * 256;
        if (i < 2112) {
          int r = i / 528, rem = i - r * 528, col = rem >> 3, ch = rem & 7;
          *(uint2*)(&Xs[cur ^ 1][(r * 66 + col) * 36 + ch * 4]) = st[j];
        }
      }
      __syncthreads();
    }
  }
  const int oBase = oT * 128 + wo * 64 + lg * 4;
  const int pxBase = pxT * 128 + wp_ * 64 + l15;
#pragma unroll
  for (int rr = 0; rr < 4; ++rr) {
#pragma unroll
    for (int ss = 0; ss < 4; ++ss) {
      int px = pxBase + ss * 16;
#pragma unroll
      for (int k = 0; k < 4; ++k) {
        int o = oBase + rr * 16 + k;
        float val = acc[rr][ss][k];
        if (scs) {
          int gx = px & 63;
          val += scs[((size_t)b * COUT + o) * P1 + pxT * 32 + (gx >> 1)] + scb[o];
        }
        Y[((size_t)b * COUT + o) * 4096 + px] = val;
      }
    }
  }
}

extern "C" void kernel_launch(void* const* d_in, const int* in_sizes, int n_in,
                              void* d_out, int out_size, void* d_ws, size_t ws_size,
                              hipStream_t stream) {
  const float* x      = (const float*)d_in[0];
  const float* gcond  = (const float*)d_in[1];
  const float* wemb   = (const float*)d_in[2];
  const int*   mask   = (const int*)d_in[3];
  const float* w_img1 = (const float*)d_in[4];
  const float* w_img2 = (const float*)d_in[5];
  const float* w_c1   = (const float*)d_in[6];
  const float* w_c2   = (const float*)d_in[7];
  const float* bn1_w  = (const float*)d_in[8];
  const float* bn1_b  = (const float*)d_in[9];
  const float* bn2_w  = (const float*)d_in[10];
  const float* bn2_b  = (const float*)d_in[11];
  const float* w_g1   = (const float*)d_in[12];
  const float* b_g1   = (const float*)d_in[13];
  const float* w_b1   = (const float*)d_in[14];
  const float* b_b1   = (const float*)d_in[15];
  const float* w_g2   = (const float*)d_in[16];
  const float* b_g2   = (const float*)d_in[17];
  const float* w_b2   = (const float*)d_in[18];
  const float* b_b2   = (const float*)d_in[19];
  const float* w_sc   = (const float*)d_in[20];
  const float* b_sc   = (const float*)d_in[21];
  float* out = (float*)d_out;
  float* ws = (float*)d_ws;

  const size_t MF = 16777216;  // floats per 64MB region
  float* A  = ws;
  float* Br = ws + MF;
  float* Cr = ws + 2 * MF;
  float* SM = ws + 3 * MF;
  float* wdn   = SM;                     // 131072
  float* mean1 = SM + 131072;
  float* rstd1 = mean1 + 512;
  float* mean2 = rstd1 + 512;
  float* rstd2 = mean2 + 256;
  float* gvec1 = rstd2 + 256;            // 8192
  float* bvec1 = gvec1 + 8192;
  float* gvec2 = bvec1 + 8192;           // 4096
  float* bvec2 = gvec2 + 4096;
  float* wsp   = bvec2 + 4096;
  u16* Wp1 = (u16*)wsp;                  // 9*256*512 ushorts
  u16* Wp2 = (u16*)(wsp + 655360);       // 9*256*256 ushorts

  float* img1   = A;                     // 4M floats
  float* ctx1   = A + 4194304;           // 4M floats
  u16*   Xt1    = (u16*)(A + 8388608);   // 8.4M u16 NHWC bf16
  float* conv1o = Cr;                    // 16M floats
  float* img2   = Br;                    // 16M floats
  float* ctx2   = A;                     // reuse (all of A dead after conv1)
  u16*   Xt2    = (u16*)Br;              // reuse (img2 dead after attnctx2)
  float* scs    = Cr;                    // reuse (conv1o dead after gbact2)

  // ---- stage 1 ----
  bn_stats_kernel<<<dim3(CIN1), dim3(256), 0, stream>>>(x, mean1, rstd1, CIN1, P1);
  wdn_kernel<<<dim3(NB * LL), dim3(64), 0, stream>>>(wemb, wdn);
  pack_w_kernel<<<dim3(COUT * CIN1 / 256), dim3(256), 0, stream>>>(w_c1, Wp1, COUT, CIN1);
  pack_w_kernel<<<dim3(COUT * COUT / 256), dim3(256), 0, stream>>>(w_c2, Wp2, COUT, COUT);
  gemm_mfma_kernel<<<dim3(P1 / 128, TD / 128, NB), dim3(256), 0, stream>>>(
      w_img1, CIN1, 0, x, nullptr, img1, TD, CIN1, P1);
  attnctx_kernel<<<dim3(P1 / 64, NB), dim3(256), 0, stream>>>(img1, wdn, mask, ctx1, P1);
  gvec_kernel<<<dim3(CIN1 / 64, NB), dim3(64), 0, stream>>>(w_g1, b_g1, gcond, gvec1, CIN1);
  gvec_kernel<<<dim3(CIN1 / 64, NB), dim3(64), 0, stream>>>(w_b1, b_b1, gcond, bvec1, CIN1);
  gbact_kernel<<<dim3(P1 / 128, CIN1 / 128, NB), dim3(256), 0, stream>>>(
      w_g1, w_b1, ctx1, gvec1, bvec1, x, mean1, rstd1, bn1_w, bn1_b, Xt1, CIN1, P1);
  conv_mfma_kernel<CIN1, true><<<dim3(32, 2, NB), dim3(256), 0, stream>>>(
      Wp1, Xt1, nullptr, nullptr, conv1o);

  // ---- stage 2 ----
  bn_stats_kernel<<<dim3(COUT), dim3(256), 0, stream>>>(conv1o, mean2, rstd2, COUT, P2);
  gemm_mfma_kernel<<<dim3(P2 / 128, TD / 128, NB), dim3(256), 0, stream>>>(
      w_img2, COUT, 0, conv1o, nullptr, img2, TD, COUT, P2);
  attnctx_kernel<<<dim3(P2 / 64, NB), dim3(256), 0, stream>>>(img2, wdn, mask, ctx2, P2);
  gvec_kernel<<<dim3(COUT / 64, NB), dim3(64), 0, stream>>>(w_g2, b_g2, gcond, gvec2, COUT);
  gvec_kernel<<<dim3(COUT / 64, NB), dim3(64), 0, stream>>>(w_b2, b_b2, gcond, bvec2, COUT);
  gbact_kernel<<<dim3(P2 / 128, COUT / 128, NB), dim3(256), 0, stream>>>(
      w_g2, w_b2, ctx2, gvec2, bvec2, conv1o, mean2, rstd2, bn2_w, bn2_b, Xt2, COUT, P2);
  gemm_mfma_kernel<<<dim3(P1 / 128, COUT / 128, NB), dim3(256), 0, stream>>>(
      w_sc, CIN1, 0, x, nullptr, scs, COUT, CIN1, P1);
  conv_mfma_kernel<COUT, false><<<dim3(32, 2, NB), dim3(256), 0, stream>>>(
      Wp2, Xt2, scs, b_sc, out);
}